// Round 14
// baseline (82.302 us; speedup 1.0000x reference)
//
#include <hip/hip_runtime.h>
#include <hip/hip_bf16.h>
#include <stdint.h>

constexpr int kB = 8, kH = 8, kS = 1024, kD = 512, kDH = 64;
constexpr float kNeg = -1e9f;
// 1/sqrt(64) * log2(e): QK^T scores scaled directly into exp2 domain
constexpr float kScaleLog2e = 0.125f * 1.4426950408889634f;

typedef __attribute__((ext_vector_type(8))) short bf16x8;
typedef __attribute__((ext_vector_type(4))) float f32x4;
typedef __attribute__((ext_vector_type(4))) unsigned short u16x4;

__device__ __forceinline__ unsigned short f2bf(float f) {
  union { float f; unsigned int u; } a; a.f = f;
  return (unsigned short)((a.u + 0x7FFFu + ((a.u >> 16) & 1u)) >> 16);
}

// packed 2xf32 -> 2xbf16 (RNE) in one v_cvt_pk_bf16_f32
__device__ __forceinline__ unsigned int pk2bf(float lo, float hi) {
  union { __hip_bfloat162 h; unsigned int u; } cv;
  cv.h = __float22bfloat162_rn(make_float2(lo, hi));
  return cv.u;
}

// Pinned global loads (inline asm: cannot be sunk/CSE'd/re-materialized).
__device__ __forceinline__ uint4 gload16(const void* p) {
  uint4 r;
  asm volatile("global_load_dwordx4 %0, %1, off" : "=v"(r) : "v"(p));
  return r;
}
__device__ __forceinline__ int gload4(const void* p) {
  int r;
  asm volatile("global_load_dword %0, %1, off" : "=v"(r) : "v"(p));
  return r;
}
// Counted vmem wait: wait until <= N loads outstanding. sched_barrier pins
// dependent LDS writes below the wait (rule #18).
#define WAIT_VMCNT(N) do { \
  asm volatile("s_waitcnt vmcnt(" #N ")" ::: "memory"); \
  __builtin_amdgcn_sched_barrier(0); } while (0)

__device__ __forceinline__ uint4 cvt4(uint4 a, uint4 b) {
  uint4 r;
  r.x = pk2bf(__uint_as_float(a.x), __uint_as_float(a.y));
  r.y = pk2bf(__uint_as_float(a.z), __uint_as_float(a.w));
  r.z = pk2bf(__uint_as_float(b.x), __uint_as_float(b.y));
  r.w = pk2bf(__uint_as_float(b.z), __uint_as_float(b.w));
  return r;
}

#if __has_builtin(__builtin_amdgcn_exp2f)
#define EXP2F(x) __builtin_amdgcn_exp2f(x)
#else
#define EXP2F(x) exp2f(x)
#endif

// ---------------------------------------------------------------------------
// Kernel 0: W (3x512x512 f32) -> bf16 into d_out (dead scratch until attn).
// ---------------------------------------------------------------------------
__global__ __launch_bounds__(256)
void wcvt_kernel(const float* __restrict__ wq, const float* __restrict__ wk,
                 const float* __restrict__ wv, unsigned short* __restrict__ wout)
{
  const int tid = blockIdx.x * 256 + threadIdx.x;   // 0..196607
  const int z = tid >> 16;
  const int i = (tid & 65535) * 4;
  const float* W = (z == 0) ? wq : (z == 1) ? wk : wv;
  float4 v4 = *(const float4*)(W + i);
  u16x4 pk;
  pk[0] = f2bf(v4.x); pk[1] = f2bf(v4.y); pk[2] = f2bf(v4.z); pk[3] = f2bf(v4.w);
  *(u16x4*)(wout + (size_t)z * 262144 + i) = pk;
}

// ---------------------------------------------------------------------------
// Kernel 1: C = relu(X @ W^T + bias). R13 diagnosis: 128x128 tiling moved
// 294 MB through L2/L3 in 39us (~7.5 TB/s) — cache-BW-bound, invariant to
// scheduling. This round: 128m x 256n tile (384 blocks, 256 thr, 4 waves,
// wave-tile 64x128, acc[4][8]) -> staged traffic 196 MB (-33%), half the
// barriers per output. Single LDS buffer (55.3 KB, 2 blk/CU), 1-deep pinned
// prefetch. MFMA operands swapped; epilogue stores packed 8B u16x4.
//   Q,K: [b*H+h][s][64]; V: [b*H+h][d][s] with s k-permuted per 64-block.
// ---------------------------------------------------------------------------
__global__ __launch_bounds__(256)
void qkv_gemm_kernel(const float* __restrict__ xq, const float* __restrict__ xk,
                     const float* __restrict__ xv,
                     const unsigned short* __restrict__ wbf,
                     const float* __restrict__ bq, const float* __restrict__ bk,
                     const float* __restrict__ bv,
                     unsigned short* __restrict__ wsout)
{
  __shared__ __align__(16) unsigned short As[128][72];
  __shared__ __align__(16) unsigned short Bs[256][72];

  // decode XCD-swizzled flat id: group gg=(z*64+y) pinned to XCD gg%8,
  // so the 2 n-blocks sharing an A-panel land on one XCD's L2.
  const int bid = blockIdx.x;                // 0..383
  const int xcd = bid & 7;
  const int j = bid >> 3;                    // 0..47
  const int x = j & 1;                       // n-tile 0..1 (256 wide)
  const int gg = (j >> 1) * 8 + xcd;         // 0..191
  const int z = gg >> 6;                     // 0..2
  const int y = gg & 63;                     // m-tile 0..63 (128 tall)

  const float* X    = (z == 0) ? xq : (z == 1) ? xk : xv;
  const unsigned short* Wb = wbf + (size_t)z * 262144;
  const float* bias = (z == 0) ? bq : (z == 1) ? bk : bv;
  unsigned short* out = wsout + (size_t)z * (kB * kS * kD);

  const int m0 = y * 128;
  const int n0 = x * 256;
  const int t = threadIdx.x;
  const int lane = t & 63;
  const int w = t >> 6;                      // 0..3
  const int wr = w >> 1, wc = w & 1;         // wave-tile 64m x 128n
  const int l16 = lane & 15, lg = lane >> 4;

  const int row = t >> 3, c8 = (t & 7) * 8;  // staging coords
  const float* Xr = X + (size_t)(m0 + row) * kD + c8;          // rows +0,32,64,96
  const unsigned short* Wr = Wb + (size_t)(n0 + row) * kD + c8; // rows +0..224

  f32x4 acc[4][8] = {};
  uint4 pa0, pa1, pa2, pa3, pa4, pa5, pa6, pa7;   // A f32 bits (4 rows x 2)
  uint4 pb0, pb1, pb2, pb3, pb4, pb5, pb6, pb7;   // B bf16 (8 rows)

  auto issue = [&](int kt) {
    pa0 = gload16(Xr + kt);             pa1 = gload16(Xr + kt + 4);
    pa2 = gload16(Xr + 32 * kD + kt);   pa3 = gload16(Xr + 32 * kD + kt + 4);
    pa4 = gload16(Xr + 64 * kD + kt);   pa5 = gload16(Xr + 64 * kD + kt + 4);
    pa6 = gload16(Xr + 96 * kD + kt);   pa7 = gload16(Xr + 96 * kD + kt + 4);
    pb0 = gload16(Wr + kt);             pb1 = gload16(Wr + 32 * kD + kt);
    pb2 = gload16(Wr + 64 * kD + kt);   pb3 = gload16(Wr + 96 * kD + kt);
    pb4 = gload16(Wr + 128 * kD + kt);  pb5 = gload16(Wr + 160 * kD + kt);
    pb6 = gload16(Wr + 192 * kD + kt);  pb7 = gload16(Wr + 224 * kD + kt);
  };
  auto lds_write = [&]() {
    *(uint4*)&As[row][c8]       = cvt4(pa0, pa1);
    *(uint4*)&As[row + 32][c8]  = cvt4(pa2, pa3);
    *(uint4*)&As[row + 64][c8]  = cvt4(pa4, pa5);
    *(uint4*)&As[row + 96][c8]  = cvt4(pa6, pa7);
    *(uint4*)&Bs[row][c8]       = pb0;
    *(uint4*)&Bs[row + 32][c8]  = pb1;
    *(uint4*)&Bs[row + 64][c8]  = pb2;
    *(uint4*)&Bs[row + 96][c8]  = pb3;
    *(uint4*)&Bs[row + 128][c8] = pb4;
    *(uint4*)&Bs[row + 160][c8] = pb5;
    *(uint4*)&Bs[row + 192][c8] = pb6;
    *(uint4*)&Bs[row + 224][c8] = pb7;
  };
  auto mfma_phase = [&]() {
#pragma unroll
    for (int kk = 0; kk < 2; ++kk) {
      bf16x8 av[4], bv[8];
#pragma unroll
      for (int mf = 0; mf < 4; ++mf)
        av[mf] = *(const bf16x8*)&As[wr * 64 + mf * 16 + l16][kk * 32 + lg * 8];
#pragma unroll
      for (int nf = 0; nf < 8; ++nf)
        bv[nf] = *(const bf16x8*)&Bs[wc * 128 + nf * 16 + l16][kk * 32 + lg * 8];
#pragma unroll
      for (int nf = 0; nf < 8; ++nf)
#pragma unroll
        for (int mf = 0; mf < 4; ++mf)
          acc[mf][nf] = __builtin_amdgcn_mfma_f32_16x16x32_bf16(bv[nf], av[mf], acc[mf][nf], 0, 0, 0);
    }
  };

  issue(0);
#pragma unroll
  for (int i = 0; i < 8; ++i) {
    if (i) __syncthreads();       // prior tile's LDS reads done
    WAIT_VMCNT(0);                // this tile's 16 loads landed
    lds_write();
    if (i < 7) issue((i + 1) * 64);   // in flight across barrier + MFMA
    __syncthreads();
    mfma_phase();
  }

  // epilogue: acc[mf][nf] row = n-dim (wc*128+nf*16+lg*4+r), col = m-dim
  // (wr*64+mf*16+l16). All stores are packed 8B u16x4.
  if (z == 2) {
    // V^T: [bh][d][s'], s' k-permuted: slot = l16*4 + mf within each 64-block
    const int mmbase = m0 + wr * 64;
    const int b_ = mmbase >> 10, sbase = mmbase & 1023;
#pragma unroll
    for (int nf = 0; nf < 8; ++nf) {
#pragma unroll
      for (int r = 0; r < 4; ++r) {
        const int n = n0 + wc * 128 + nf * 16 + lg * 4 + r;
        const float bval = bias[n];
        const int h = n >> 6, dd = n & 63;
        u16x4 pk;
#pragma unroll
        for (int mf = 0; mf < 4; ++mf) {
          float vv = acc[mf][nf][r] + bval;
          vv = vv > 0.f ? vv : 0.f;
          pk[mf] = f2bf(vv);
        }
        *(u16x4*)&out[((size_t)((b_ * kH + h) * kDH + dd)) * kS + sbase + l16 * 4] = pk;
      }
    }
  } else {
    // Q,K: [bh][s][d], 4 consecutive d per store
#pragma unroll
    for (int mf = 0; mf < 4; ++mf) {
      const int mm = m0 + wr * 64 + mf * 16 + l16;
      const int b_ = mm >> 10, s = mm & 1023;
#pragma unroll
      for (int nf = 0; nf < 8; ++nf) {
        const int nbase = n0 + wc * 128 + nf * 16 + lg * 4;
        const int h = nbase >> 6, dd = nbase & 63;
        u16x4 pk;
#pragma unroll
        for (int r = 0; r < 4; ++r) {
          float vv = acc[mf][nf][r] + bias[nbase + r];
          vv = vv > 0.f ? vv : 0.f;
          pk[r] = f2bf(vv);
        }
        *(u16x4*)&out[((size_t)(b_ * kH + h) * kS + s) * kDH + dd] = pk;
      }
    }
  }
}

// ---------------------------------------------------------------------------
// Kernel 2: flash attention (unchanged from R13). 512 blocks (bh x 8 q-tiles
// of 128 rows), 4 waves x 32 q-rows: each K/V fragment read feeds two MFMA.
// 2-deep pinned prefetch, counted vmcnt(5); LDS double-buffered, one
// barrier/step. No-max exp2 softmax; l via MFMA vs ones; P truncated via
// v_perm into the k-permuted slot layout (matches V^T's k-order).
// Writes y (pre-residual, pre-qmask) f32 into d_out, layout [b][s][512].
// ---------------------------------------------------------------------------
__global__ __launch_bounds__(256)
void attn_kernel(const unsigned short* __restrict__ ws,
                 const int* __restrict__ key_mask,
                 float* __restrict__ y)
{
  __shared__ __align__(16) unsigned short Ks[2][64][72];
  __shared__ __align__(16) unsigned short Vts[2][64][72]; // V^T: [d][k-slot]
  __shared__ __align__(16) unsigned short Ps[4][32][72];  // P: [q][k-slot]
  __shared__ float kmadd[2][64];

  const unsigned short* Qw = ws;
  const unsigned short* Kw = ws + (size_t)1 * kB * kS * kD;
  const unsigned short* Vw = ws + (size_t)2 * kB * kS * kD;

  const int bid = blockIdx.x;
  const int xcd = bid & 7;
  const int j = bid >> 3;
  const int qx = j & 7;                    // q-tile 0..7 (128 rows each)
  const int bh = (j >> 3) * 8 + xcd;       // 0..63

  const int q0 = qx * 128;
  const int t = threadIdx.x;
  const int w = t >> 6, lane = t & 63;
  const int l16 = lane & 15, lg = lane >> 4;
  const int b_ = bh / kH, h = bh % kH;

  const unsigned short* Qb = Qw + ((size_t)bh * kS + q0) * kDH;
  const unsigned short* Kb = Kw + (size_t)bh * kS * kDH;
  const unsigned short* Vb = Vw + (size_t)bh * kDH * kS;   // [64][1024] k-perm
  const int* km = key_mask + (bh % kB) * kS;

  const int srow = t >> 3, sc8 = (t & 7) * 8;
  const unsigned short* KbR0 = Kb + (size_t)srow * kDH + sc8;
  const unsigned short* KbR1 = Kb + (size_t)(srow + 32) * kDH + sc8;
  const unsigned short* VbR0 = Vb + (size_t)srow * kS + sc8;
  const unsigned short* VbR1 = Vb + (size_t)(srow + 32) * kS + sc8;

  // Q fragments: wave covers q-rows w*32 .. w*32+31 (2 sub-tiles u=0,1)
  bf16x8 aq[2][2];
#pragma unroll
  for (int u = 0; u < 2; ++u)
#pragma unroll
    for (int kk = 0; kk < 2; ++kk)
      aq[u][kk] = *(const bf16x8*)(Qb + (size_t)(w * 32 + u * 16 + l16) * kDH + kk * 32 + lg * 8);

  bf16x8 vone;
#pragma unroll
  for (int jj = 0; jj < 8; ++jj) vone[jj] = (short)0x3F80;  // bf16 1.0

  f32x4 o[2][4] = {};
  f32x4 lacc[2] = {};

  uint4 ka0, ka1, va0, va1; int kma;
  uint4 kb0, kb1, vb0, vb1; int kmb;

  auto issueA = [&](int kv0) {
    ka0 = gload16(KbR0 + (size_t)kv0 * kDH);
    ka1 = gload16(KbR1 + (size_t)kv0 * kDH);
    va0 = gload16(VbR0 + kv0);
    va1 = gload16(VbR1 + kv0);
    kma = gload4(km + kv0 + (t & 63));
  };
  auto issueB = [&](int kv0) {
    kb0 = gload16(KbR0 + (size_t)kv0 * kDH);
    kb1 = gload16(KbR1 + (size_t)kv0 * kDH);
    vb0 = gload16(VbR0 + kv0);
    vb1 = gload16(VbR1 + kv0);
    kmb = gload4(km + kv0 + (t & 63));
  };
  auto writeA = [&]() {   // buf 0
    *(uint4*)&Ks[0][srow][sc8]       = ka0;
    *(uint4*)&Ks[0][srow + 32][sc8]  = ka1;
    *(uint4*)&Vts[0][srow][sc8]      = va0;
    *(uint4*)&Vts[0][srow + 32][sc8] = va1;
    if (t < 64) kmadd[0][t] = kma ? 0.f : kNeg;
  };
  auto writeB = [&]() {   // buf 1
    *(uint4*)&Ks[1][srow][sc8]       = kb0;
    *(uint4*)&Ks[1][srow + 32][sc8]  = kb1;
    *(uint4*)&Vts[1][srow][sc8]      = vb0;
    *(uint4*)&Vts[1][srow + 32][sc8] = vb1;
    if (t < 64) kmadd[1][t] = kmb ? 0.f : kNeg;
  };
  auto compute = [&](int buf) {
    f32x4 sc[2][4] = {};
#pragma unroll
    for (int kk = 0; kk < 2; ++kk) {
#pragma unroll
      for (int nf = 0; nf < 4; ++nf) {
        bf16x8 bfr = *(const bf16x8*)&Ks[buf][nf * 16 + l16][kk * 32 + lg * 8];
#pragma unroll
        for (int u = 0; u < 2; ++u)
          sc[u][nf] = __builtin_amdgcn_mfma_f32_16x16x32_bf16(aq[u][kk], bfr, sc[u][nf], 0, 0, 0);
      }
    }
    float madd[4];
#pragma unroll
    for (int nf = 0; nf < 4; ++nf) madd[nf] = kmadd[buf][nf * 16 + l16];
#pragma unroll
    for (int u = 0; u < 2; ++u) {
#pragma unroll
      for (int r = 0; r < 4; ++r) {
        const float p0 = EXP2F(fmaf(sc[u][0][r], kScaleLog2e, madd[0]));
        const float p1 = EXP2F(fmaf(sc[u][1][r], kScaleLog2e, madd[1]));
        const float p2 = EXP2F(fmaf(sc[u][2][r], kScaleLog2e, madd[2]));
        const float p3 = EXP2F(fmaf(sc[u][3][r], kScaleLog2e, madd[3]));
        const int prow = u * 16 + lg * 4 + r;
        uint2 pw;
        pw.x = __builtin_amdgcn_perm(__float_as_uint(p1), __float_as_uint(p0), 0x07060302u);
        pw.y = __builtin_amdgcn_perm(__float_as_uint(p3), __float_as_uint(p2), 0x07060302u);
        *(uint2*)&Ps[w][prow][l16 * 4] = pw;
      }
    }
#pragma unroll
    for (int kk = 0; kk < 2; ++kk) {
      bf16x8 a0 = *(const bf16x8*)&Ps[w][l16][kk * 32 + lg * 8];
      bf16x8 a1 = *(const bf16x8*)&Ps[w][16 + l16][kk * 32 + lg * 8];
#pragma unroll
      for (int nd = 0; nd < 4; ++nd) {
        bf16x8 bfr = *(const bf16x8*)&Vts[buf][nd * 16 + l16][kk * 32 + lg * 8];
        o[0][nd] = __builtin_amdgcn_mfma_f32_16x16x32_bf16(a0, bfr, o[0][nd], 0, 0, 0);
        o[1][nd] = __builtin_amdgcn_mfma_f32_16x16x32_bf16(a1, bfr, o[1][nd], 0, 0, 0);
      }
      lacc[0] = __builtin_amdgcn_mfma_f32_16x16x32_bf16(a0, vone, lacc[0], 0, 0, 0);
      lacc[1] = __builtin_amdgcn_mfma_f32_16x16x32_bf16(a1, vone, lacc[1], 0, 0, 0);
    }
  };

  issueA(0);
  issueB(64);
  for (int i = 0; i < 14; i += 2) {
    WAIT_VMCNT(5);
    writeA();
    issueA((i + 2) * 64);
    __syncthreads();
    compute(0);
    WAIT_VMCNT(5);
    writeB();
    issueB((i + 3) * 64);
    __syncthreads();
    compute(1);
  }
  WAIT_VMCNT(5);
  writeA();
  __syncthreads();
  compute(0);
  WAIT_VMCNT(0);
  writeB();
  __syncthreads();
  compute(1);

#pragma unroll
  for (int u = 0; u < 2; ++u) {
    float rinv[4];
#pragma unroll
    for (int r = 0; r < 4; ++r) rinv[r] = 1.f / lacc[u][r];
#pragma unroll
    for (int nd = 0; nd < 4; ++nd) {
#pragma unroll
      for (int r = 0; r < 4; ++r) {
        const int srowq = q0 + w * 32 + u * 16 + lg * 4 + r;
        y[((size_t)b_ * kS + srowq) * kD + h * kDH + nd * 16 + l16] = o[u][nd][r] * rinv[r];
      }
    }
  }
}

// ---------------------------------------------------------------------------
// Kernel 3: out = LN(qmask*y + q) * gamma + beta, in-place on d_out.
// One wave per row; qmask row = ((b*H + h) % B)  (same reference quirk).
// ---------------------------------------------------------------------------
__global__ __launch_bounds__(256)
void ln_kernel(const float* __restrict__ y, const float* __restrict__ q,
               const int* __restrict__ qmask,
               const float* __restrict__ gamma, const float* __restrict__ beta,
               float* __restrict__ out)
{
  const int w = threadIdx.x >> 6, lane = threadIdx.x & 63;
  const int row = blockIdx.x * 4 + w;            // 0..8191
  const int b_ = row >> 10, s = row & 1023;
  const int d0 = lane * 8;
  const int h = d0 >> 6;

  const float* yp = y + (size_t)row * kD + d0;
  const float* qp = q + (size_t)row * kD + d0;
  const int qm = qmask[((b_ * kH + h) % kB) * kS + s];

  float4 y0 = *(const float4*)yp, y1 = *(const float4*)(yp + 4);
  float4 q0 = *(const float4*)qp, q1 = *(const float4*)(qp + 4);
  float vals[8] = { y0.x, y0.y, y0.z, y0.w, y1.x, y1.y, y1.z, y1.w };
  float qs[8]   = { q0.x, q0.y, q0.z, q0.w, q1.x, q1.y, q1.z, q1.w };

  float sum = 0.f, ss = 0.f;
#pragma unroll
  for (int j = 0; j < 8; ++j) {
    const float val = (qm ? vals[j] : 0.f) + qs[j];
    vals[j] = val; sum += val; ss += val * val;
  }
#pragma unroll
  for (int off = 1; off < 64; off <<= 1) {
    sum += __shfl_xor(sum, off);
    ss  += __shfl_xor(ss, off);
  }
  const float mu = sum * (1.f / kD);
  const float var = ss * (1.f / kD) - mu * mu;
  const float rstd = rsqrtf(var + 1e-6f);

  float4 g0 = *(const float4*)(gamma + d0), g1 = *(const float4*)(gamma + d0 + 4);
  float4 be0 = *(const float4*)(beta + d0), be1 = *(const float4*)(beta + d0 + 4);
  float gs[8] = { g0.x, g0.y, g0.z, g0.w, g1.x, g1.y, g1.z, g1.w };
  float bs[8] = { be0.x, be0.y, be0.z, be0.w, be1.x, be1.y, be1.z, be1.w };

  float4 o0, o1;
  o0.x = gs[0] * (vals[0] - mu) * rstd + bs[0];
  o0.y = gs[1] * (vals[1] - mu) * rstd + bs[1];
  o0.z = gs[2] * (vals[2] - mu) * rstd + bs[2];
  o0.w = gs[3] * (vals[3] - mu) * rstd + bs[3];
  o1.x = gs[4] * (vals[4] - mu) * rstd + bs[4];
  o1.y = gs[5] * (vals[5] - mu) * rstd + bs[5];
  o1.z = gs[6] * (vals[6] - mu) * rstd + bs[6];
  o1.w = gs[7] * (vals[7] - mu) * rstd + bs[7];
  *(float4*)(out + (size_t)row * kD + d0) = o0;
  *(float4*)(out + (size_t)row * kD + d0 + 4) = o1;
}

extern "C" void kernel_launch(void* const* d_in, const int* in_sizes, int n_in,
                              void* d_out, int out_size, void* d_ws, size_t ws_size,
                              hipStream_t stream) {
  const float* q  = (const float*)d_in[0];
  const float* k  = (const float*)d_in[1];
  const float* v  = (const float*)d_in[2];
  const int* qmask = (const int*)d_in[3];
  const int* kmask = (const int*)d_in[4];
  const float* Wq = (const float*)d_in[5];
  const float* bq = (const float*)d_in[6];
  const float* Wk = (const float*)d_in[7];
  const float* bk = (const float*)d_in[8];
  const float* Wv = (const float*)d_in[9];
  const float* bv = (const float*)d_in[10];
  const float* gamma = (const float*)d_in[11];
  const float* beta  = (const float*)d_in[12];
  float* out = (float*)d_out;
  unsigned short* wsqkv = (unsigned short*)d_ws;  // 3 x 8MB bf16: Q,K,V^T(k-perm)
  // d_out doubles as scratch for bf16 W until attn overwrites it
  unsigned short* wbf = (unsigned short*)d_out;

  wcvt_kernel<<<768, 256, 0, stream>>>(Wq, Wk, Wv, wbf);
  qkv_gemm_kernel<<<384, 256, 0, stream>>>(
      q, k, v, wbf, bq, bk, bv, wsqkv);
  attn_kernel<<<512, 256, 0, stream>>>(wsqkv, kmask, out);
  ln_kernel<<<2048, 256, 0, stream>>>(out, q, qmask, gamma, beta, out);
}

// Round 15
// 78.314 us; speedup vs baseline: 1.0509x; 1.0509x over previous
//
#include <hip/hip_runtime.h>
#include <hip/hip_bf16.h>
#include <stdint.h>

constexpr int kB = 8, kH = 8, kS = 1024, kD = 512, kDH = 64;
constexpr float kNeg = -1e9f;
constexpr float kScaleLog2e = 0.125f * 1.4426950408889634f;

typedef __attribute__((ext_vector_type(8))) short bf16x8;
typedef __attribute__((ext_vector_type(4))) float f32x4;
typedef __attribute__((ext_vector_type(4))) unsigned short u16x4;

__device__ __forceinline__ unsigned short f2bf(float f) {
  union { float f; unsigned int u; } a; a.f = f;
  return (unsigned short)((a.u + 0x7FFFu + ((a.u >> 16) & 1u)) >> 16);
}
__device__ __forceinline__ unsigned int pk2bf(float lo, float hi) {
  union { __hip_bfloat162 h; unsigned int u; } cv;
  cv.h = __float22bfloat162_rn(make_float2(lo, hi));
  return cv.u;
}
// Pinned global loads (inline asm: cannot be sunk/CSE'd/re-materialized).
__device__ __forceinline__ uint4 gload16(const void* p) {
  uint4 r;
  asm volatile("global_load_dwordx4 %0, %1, off" : "=v"(r) : "v"(p));
  return r;
}
__device__ __forceinline__ int gload4(const void* p) {
  int r;
  asm volatile("global_load_dword %0, %1, off" : "=v"(r) : "v"(p));
  return r;
}
#define WAIT_VMCNT(N) do { \
  asm volatile("s_waitcnt vmcnt(" #N ")" ::: "memory"); \
  __builtin_amdgcn_sched_barrier(0); } while (0)

__device__ __forceinline__ uint4 cvt4(uint4 a, uint4 b) {
  uint4 r;
  r.x = pk2bf(__uint_as_float(a.x), __uint_as_float(a.y));
  r.y = pk2bf(__uint_as_float(a.z), __uint_as_float(a.w));
  r.z = pk2bf(__uint_as_float(b.x), __uint_as_float(b.y));
  r.w = pk2bf(__uint_as_float(b.z), __uint_as_float(b.w));
  return r;
}
// async global -> LDS, 16B per lane. LDS dest = (wave-uniform base) + lane*16;
// global src is PER-LANE (this is how the source-side swizzle is applied).
__device__ __forceinline__ void gll16(const unsigned short* g, unsigned short* l) {
  __builtin_amdgcn_global_load_lds(
      (const __attribute__((address_space(1))) unsigned int*)(g),
      (__attribute__((address_space(3))) unsigned int*)(l), 16, 0, 0);
}

#if __has_builtin(__builtin_amdgcn_exp2f)
#define EXP2F(x) __builtin_amdgcn_exp2f(x)
#else
#define EXP2F(x) exp2f(x)
#endif

// ---------------------------------------------------------------------------
// Kernel 0: convert W (3x512x512) -> wbf (d_out scratch) and, if do_x, X
// (q,k,v 3x8192x512) -> xbf (ws+24MB), both plain row-major bf16.
// ---------------------------------------------------------------------------
__global__ __launch_bounds__(256)
void cvt_all(const float* __restrict__ xq, const float* __restrict__ xk,
             const float* __restrict__ xv,
             const float* __restrict__ wq, const float* __restrict__ wk,
             const float* __restrict__ wv,
             unsigned short* __restrict__ xbf, unsigned short* __restrict__ wbf,
             int do_x)
{
  constexpr int kXElems = 3 * 4194304;       // 12,582,912 f32
  constexpr int kTotal  = kXElems + 3 * 262144;
  for (int idx = blockIdx.x * 256 + threadIdx.x; idx * 4 < kTotal;
       idx += gridDim.x * 256) {
    const int i4 = idx * 4;
    const float* src;
    unsigned short* dst;
    if (i4 < kXElems) {
      if (!do_x) continue;
      const int z = i4 >> 22, off = i4 & 4194303;
      src = ((z == 0) ? xq : (z == 1) ? xk : xv) + off;
      dst = xbf + (size_t)z * 4194304 + off;
    } else {
      const int j = i4 - kXElems;
      const int z = j >> 18, off = j & 262143;
      src = ((z == 0) ? wq : (z == 1) ? wk : wv) + off;
      dst = wbf + (size_t)z * 262144 + off;
    }
    float4 v4 = *(const float4*)src;
    u16x4 pk;
    pk[0] = f2bf(v4.x); pk[1] = f2bf(v4.y); pk[2] = f2bf(v4.z); pk[3] = f2bf(v4.w);
    *(u16x4*)dst = pk;
  }
}

// ---------------------------------------------------------------------------
// Kernel 1a (preferred): GEMM via global_load_lds (m97-structure). 256 thr,
// 4 waves 2x2, 128x128 tile, BK=64. LDS As/Bs [128][64] bf16 LINEAR (32KB);
// bank conflicts avoided by XOR-ing the 16B-chunk index with (row&7) on the
// per-lane GLOBAL source address (write side) and on the ds_read address
// (read side) — rule #21 both-sides pattern. No staging VGPRs, no cvt, no
// ds_writes: staging is 8 global_load_lds issues per thread-step.
// MFMA operands swapped; epilogue packed 8B stores (as R13).
// ---------------------------------------------------------------------------
__global__ __launch_bounds__(256)
void qkv_gemm_lds(const unsigned short* __restrict__ xbf,
                  const unsigned short* __restrict__ wbf,
                  const float* __restrict__ bq, const float* __restrict__ bk,
                  const float* __restrict__ bv,
                  unsigned short* __restrict__ wsout)
{
  __shared__ __align__(16) unsigned short As[128][64];
  __shared__ __align__(16) unsigned short Bs[128][64];

  const int bid = blockIdx.x;
  const int xcd = bid & 7;
  const int j = bid >> 3;
  const int x = j & 3;
  const int g = (j >> 2) * 8 + xcd;        // 0..191
  const int z = g >> 6;
  const int y = g & 63;

  const unsigned short* Xb = xbf + (size_t)z * 4194304;
  const unsigned short* Wb = wbf + (size_t)z * 262144;
  const float* bias = (z == 0) ? bq : (z == 1) ? bk : bv;
  unsigned short* out = wsout + (size_t)z * (kB * kS * kD);

  const int m0 = y * 128;
  const int n0 = x * 128;
  const int t = threadIdx.x;
  const int lane = t & 63;
  const int w = t >> 6;
  const int wr = w >> 1, wc = w & 1;       // 2x2 waves, 64x64 out each
  const int l16 = lane & 15, lg = lane >> 4;

  f32x4 acc[4][4] = {};

  auto issue = [&](int kt) {
#pragma unroll
    for (int i = 0; i < 4; ++i) {
      const int s = w * 64 + lane + 256 * i;     // slot 0..1023
      const int r = s >> 3, c = s & 7;
      const int cs = (c ^ (r & 7)) * 8;          // source-side chunk swizzle
      unsigned short* ldsoff = (unsigned short*)&As[0][0] + (size_t)(w * 64 + 256 * i) * 8;
      gll16(Xb + (size_t)(m0 + r) * kD + kt + cs, ldsoff);
      unsigned short* ldsoffB = (unsigned short*)&Bs[0][0] + (size_t)(w * 64 + 256 * i) * 8;
      gll16(Wb + (size_t)(n0 + r) * kD + kt + cs, ldsoffB);
    }
  };
  auto mfma_phase = [&]() {
#pragma unroll
    for (int kk = 0; kk < 2; ++kk) {
      const int x0 = ((kk * 4 + lg) ^ (l16 & 7)) * 8;   // read-side swizzle
      bf16x8 av[4], bv_[4];
#pragma unroll
      for (int mf = 0; mf < 4; ++mf)
        av[mf] = *(const bf16x8*)&As[wr * 64 + mf * 16 + l16][x0];
#pragma unroll
      for (int nf = 0; nf < 4; ++nf)
        bv_[nf] = *(const bf16x8*)&Bs[wc * 64 + nf * 16 + l16][x0];
#pragma unroll
      for (int nf = 0; nf < 4; ++nf)
#pragma unroll
        for (int mf = 0; mf < 4; ++mf)
          acc[mf][nf] = __builtin_amdgcn_mfma_f32_16x16x32_bf16(bv_[nf], av[mf], acc[mf][nf], 0, 0, 0);
    }
  };

  issue(0);
#pragma unroll
  for (int i = 0; i < 8; ++i) {
    WAIT_VMCNT(0);            // this wave's gload_lds landed in LDS
    __syncthreads();          // all waves' tiles visible
    mfma_phase();
    __syncthreads();          // reads done before overwrite
    if (i < 7) issue((i + 1) * 64);
  }

  if (z == 2) {
    // V^T: [bh][d][s'], s' k-permuted: slot = l16*4 + mf within each 64-block
    const int mmbase = m0 + wr * 64;
    const int b_ = mmbase >> 10, sbase = mmbase & 1023;
#pragma unroll
    for (int nf = 0; nf < 4; ++nf) {
#pragma unroll
      for (int r = 0; r < 4; ++r) {
        const int n = n0 + wc * 64 + nf * 16 + lg * 4 + r;
        const float bval = bias[n];
        const int h = n >> 6, dd = n & 63;
        u16x4 pk;
#pragma unroll
        for (int mf = 0; mf < 4; ++mf) {
          float vv = acc[mf][nf][r] + bval;
          vv = vv > 0.f ? vv : 0.f;
          pk[mf] = f2bf(vv);
        }
        *(u16x4*)&out[((size_t)((b_ * kH + h) * kDH + dd)) * kS + sbase + l16 * 4] = pk;
      }
    }
  } else {
#pragma unroll
    for (int mf = 0; mf < 4; ++mf) {
      const int mm = m0 + wr * 64 + mf * 16 + l16;
      const int b_ = mm >> 10, s = mm & 1023;
#pragma unroll
      for (int nf = 0; nf < 4; ++nf) {
        const int nbase = n0 + wc * 64 + nf * 16 + lg * 4;
        const int h = nbase >> 6, dd = nbase & 63;
        u16x4 pk;
#pragma unroll
        for (int r = 0; r < 4; ++r) {
          float vv = acc[mf][nf][r] + bias[nbase + r];
          vv = vv > 0.f ? vv : 0.f;
          pk[r] = f2bf(vv);
        }
        *(u16x4*)&out[((size_t)(b_ * kH + h) * kS + s) * kDH + dd] = pk;
      }
    }
  }
}

// ---------------------------------------------------------------------------
// Kernel 1b (fallback if ws_size < 48MB): R13's reg-staged 2-deep GEMM.
// ---------------------------------------------------------------------------
__global__ __launch_bounds__(256)
void qkv_gemm_reg(const float* __restrict__ xq, const float* __restrict__ xk,
                  const float* __restrict__ xv,
                  const unsigned short* __restrict__ wbf,
                  const float* __restrict__ bq, const float* __restrict__ bk,
                  const float* __restrict__ bv,
                  unsigned short* __restrict__ wsout)
{
  __shared__ __align__(16) unsigned short As[2][128][72];
  __shared__ __align__(16) unsigned short Bs[2][128][72];

  const int bid = blockIdx.x;
  const int xcd = bid & 7;
  const int j = bid >> 3;
  const int x = j & 3;
  const int g = (j >> 2) * 8 + xcd;
  const int z = g >> 6;
  const int y = g & 63;

  const float* X    = (z == 0) ? xq : (z == 1) ? xk : xv;
  const unsigned short* Wb = wbf + (size_t)z * 262144;
  const float* bias = (z == 0) ? bq : (z == 1) ? bk : bv;
  unsigned short* out = wsout + (size_t)z * (kB * kS * kD);

  const int m0 = y * 128;
  const int n0 = x * 128;
  const int t = threadIdx.x;
  const int lane = t & 63;
  const int w = t >> 6;
  const int wr = w >> 1, wc = w & 1;
  const int l16 = lane & 15, lg = lane >> 4;

  const int row = t >> 3, c8 = (t & 7) * 8;
  const float* Xr = X + (size_t)(m0 + row) * kD + c8;
  const unsigned short* Wr = Wb + (size_t)(n0 + row) * kD + c8;

  f32x4 acc[4][4] = {};
  uint4 pa0, pa1, pa2, pa3, pa4, pa5, pa6, pa7, pb0, pb1, pb2, pb3;
  uint4 qa0, qa1, qa2, qa3, qa4, qa5, qa6, qa7, qb0, qb1, qb2, qb3;

  auto issueP = [&](int kt) {
    pa0 = gload16(Xr + kt);            pa1 = gload16(Xr + kt + 4);
    pa2 = gload16(Xr + 32 * kD + kt);  pa3 = gload16(Xr + 32 * kD + kt + 4);
    pa4 = gload16(Xr + 64 * kD + kt);  pa5 = gload16(Xr + 64 * kD + kt + 4);
    pa6 = gload16(Xr + 96 * kD + kt);  pa7 = gload16(Xr + 96 * kD + kt + 4);
    pb0 = gload16(Wr + kt);            pb1 = gload16(Wr + 32 * kD + kt);
    pb2 = gload16(Wr + 64 * kD + kt);  pb3 = gload16(Wr + 96 * kD + kt);
  };
  auto issueQ = [&](int kt) {
    qa0 = gload16(Xr + kt);            qa1 = gload16(Xr + kt + 4);
    qa2 = gload16(Xr + 32 * kD + kt);  qa3 = gload16(Xr + 32 * kD + kt + 4);
    qa4 = gload16(Xr + 64 * kD + kt);  qa5 = gload16(Xr + 64 * kD + kt + 4);
    qa6 = gload16(Xr + 96 * kD + kt);  qa7 = gload16(Xr + 96 * kD + kt + 4);
    qb0 = gload16(Wr + kt);            qb1 = gload16(Wr + 32 * kD + kt);
    qb2 = gload16(Wr + 64 * kD + kt);  qb3 = gload16(Wr + 96 * kD + kt);
  };
  auto writeP = [&]() {
    *(uint4*)&As[0][row][c8]      = cvt4(pa0, pa1);
    *(uint4*)&As[0][row + 32][c8] = cvt4(pa2, pa3);
    *(uint4*)&As[0][row + 64][c8] = cvt4(pa4, pa5);
    *(uint4*)&As[0][row + 96][c8] = cvt4(pa6, pa7);
    *(uint4*)&Bs[0][row][c8]      = pb0;
    *(uint4*)&Bs[0][row + 32][c8] = pb1;
    *(uint4*)&Bs[0][row + 64][c8] = pb2;
    *(uint4*)&Bs[0][row + 96][c8] = pb3;
  };
  auto writeQ = [&]() {
    *(uint4*)&As[1][row][c8]      = cvt4(qa0, qa1);
    *(uint4*)&As[1][row + 32][c8] = cvt4(qa2, qa3);
    *(uint4*)&As[1][row + 64][c8] = cvt4(qa4, qa5);
    *(uint4*)&As[1][row + 96][c8] = cvt4(qa6, qa7);
    *(uint4*)&Bs[1][row][c8]      = qb0;
    *(uint4*)&Bs[1][row + 32][c8] = qb1;
    *(uint4*)&Bs[1][row + 64][c8] = qb2;
    *(uint4*)&Bs[1][row + 96][c8] = qb3;
  };
  auto mfma_phase = [&](int buf) {
#pragma unroll
    for (int kk = 0; kk < 2; ++kk) {
      bf16x8 av[4], bv[4];
#pragma unroll
      for (int mf = 0; mf < 4; ++mf)
        av[mf] = *(const bf16x8*)&As[buf][wr * 64 + mf * 16 + l16][kk * 32 + lg * 8];
#pragma unroll
      for (int nf = 0; nf < 4; ++nf)
        bv[nf] = *(const bf16x8*)&Bs[buf][wc * 64 + nf * 16 + l16][kk * 32 + lg * 8];
#pragma unroll
      for (int nf = 0; nf < 4; ++nf)
#pragma unroll
        for (int mf = 0; mf < 4; ++mf)
          acc[mf][nf] = __builtin_amdgcn_mfma_f32_16x16x32_bf16(bv[nf], av[mf], acc[mf][nf], 0, 0, 0);
    }
  };

  issueP(0);
  issueQ(64);
#pragma unroll
  for (int i = 0; i < 6; i += 2) {
    WAIT_VMCNT(12);
    writeP();
    issueP((i + 2) * 64);
    __syncthreads();
    mfma_phase(0);
    WAIT_VMCNT(12);
    writeQ();
    issueQ((i + 3) * 64);
    __syncthreads();
    mfma_phase(1);
  }
  WAIT_VMCNT(12);
  writeP();
  __syncthreads();
  mfma_phase(0);
  WAIT_VMCNT(0);
  writeQ();
  __syncthreads();
  mfma_phase(1);

  if (z == 2) {
    const int mmbase = m0 + wr * 64;
    const int b_ = mmbase >> 10, sbase = mmbase & 1023;
#pragma unroll
    for (int nf = 0; nf < 4; ++nf) {
#pragma unroll
      for (int r = 0; r < 4; ++r) {
        const int n = n0 + wc * 64 + nf * 16 + lg * 4 + r;
        const float bval = bias[n];
        const int h = n >> 6, dd = n & 63;
        u16x4 pk;
#pragma unroll
        for (int mf = 0; mf < 4; ++mf) {
          float vv = acc[mf][nf][r] + bval;
          vv = vv > 0.f ? vv : 0.f;
          pk[mf] = f2bf(vv);
        }
        *(u16x4*)&out[((size_t)((b_ * kH + h) * kDH + dd)) * kS + sbase + l16 * 4] = pk;
      }
    }
  } else {
#pragma unroll
    for (int mf = 0; mf < 4; ++mf) {
      const int mm = m0 + wr * 64 + mf * 16 + l16;
      const int b_ = mm >> 10, s = mm & 1023;
#pragma unroll
      for (int nf = 0; nf < 4; ++nf) {
        const int nbase = n0 + wc * 64 + nf * 16 + lg * 4;
        const int h = nbase >> 6, dd = nbase & 63;
        u16x4 pk;
#pragma unroll
        for (int r = 0; r < 4; ++r) {
          float vv = acc[mf][nf][r] + bias[nbase + r];
          vv = vv > 0.f ? vv : 0.f;
          pk[r] = f2bf(vv);
        }
        *(u16x4*)&out[((size_t)(b_ * kH + h) * kS + s) * kDH + dd] = pk;
      }
    }
  }
}

// ---------------------------------------------------------------------------
// Kernel 2: flash attention (R13 verbatim). 512 blocks (bh x 8 q-tiles of
// 128 rows), 4 waves x 32 q-rows; 2-deep pinned prefetch, counted vmcnt(5);
// LDS double-buffered, one barrier/step. No-max exp2 softmax; l via MFMA vs
// ones; P truncated via v_perm into the k-permuted slot layout.
// ---------------------------------------------------------------------------
__global__ __launch_bounds__(256)
void attn_kernel(const unsigned short* __restrict__ ws,
                 const int* __restrict__ key_mask,
                 float* __restrict__ y)
{
  __shared__ __align__(16) unsigned short Ks[2][64][72];
  __shared__ __align__(16) unsigned short Vts[2][64][72];
  __shared__ __align__(16) unsigned short Ps[4][32][72];
  __shared__ float kmadd[2][64];

  const unsigned short* Qw = ws;
  const unsigned short* Kw = ws + (size_t)1 * kB * kS * kD;
  const unsigned short* Vw = ws + (size_t)2 * kB * kS * kD;

  const int bid = blockIdx.x;
  const int xcd = bid & 7;
  const int j = bid >> 3;
  const int qx = j & 7;
  const int bh = (j >> 3) * 8 + xcd;

  const int q0 = qx * 128;
  const int t = threadIdx.x;
  const int w = t >> 6, lane = t & 63;
  const int l16 = lane & 15, lg = lane >> 4;
  const int b_ = bh / kH, h = bh % kH;

  const unsigned short* Qb = Qw + ((size_t)bh * kS + q0) * kDH;
  const unsigned short* Kb = Kw + (size_t)bh * kS * kDH;
  const unsigned short* Vb = Vw + (size_t)bh * kDH * kS;
  const int* km = key_mask + (bh % kB) * kS;

  const int srow = t >> 3, sc8 = (t & 7) * 8;
  const unsigned short* KbR0 = Kb + (size_t)srow * kDH + sc8;
  const unsigned short* KbR1 = Kb + (size_t)(srow + 32) * kDH + sc8;
  const unsigned short* VbR0 = Vb + (size_t)srow * kS + sc8;
  const unsigned short* VbR1 = Vb + (size_t)(srow + 32) * kS + sc8;

  bf16x8 aq[2][2];
#pragma unroll
  for (int u = 0; u < 2; ++u)
#pragma unroll
    for (int kk = 0; kk < 2; ++kk)
      aq[u][kk] = *(const bf16x8*)(Qb + (size_t)(w * 32 + u * 16 + l16) * kDH + kk * 32 + lg * 8);

  bf16x8 vone;
#pragma unroll
  for (int jj = 0; jj < 8; ++jj) vone[jj] = (short)0x3F80;

  f32x4 o[2][4] = {};
  f32x4 lacc[2] = {};

  uint4 ka0, ka1, va0, va1; int kma;
  uint4 kb0, kb1, vb0, vb1; int kmb;

  auto issueA = [&](int kv0) {
    ka0 = gload16(KbR0 + (size_t)kv0 * kDH);
    ka1 = gload16(KbR1 + (size_t)kv0 * kDH);
    va0 = gload16(VbR0 + kv0);
    va1 = gload16(VbR1 + kv0);
    kma = gload4(km + kv0 + (t & 63));
  };
  auto issueB = [&](int kv0) {
    kb0 = gload16(KbR0 + (size_t)kv0 * kDH);
    kb1 = gload16(KbR1 + (size_t)kv0 * kDH);
    vb0 = gload16(VbR0 + kv0);
    vb1 = gload16(VbR1 + kv0);
    kmb = gload4(km + kv0 + (t & 63));
  };
  auto writeA = [&]() {
    *(uint4*)&Ks[0][srow][sc8]       = ka0;
    *(uint4*)&Ks[0][srow + 32][sc8]  = ka1;
    *(uint4*)&Vts[0][srow][sc8]      = va0;
    *(uint4*)&Vts[0][srow + 32][sc8] = va1;
    if (t < 64) kmadd[0][t] = kma ? 0.f : kNeg;
  };
  auto writeB = [&]() {
    *(uint4*)&Ks[1][srow][sc8]       = kb0;
    *(uint4*)&Ks[1][srow + 32][sc8]  = kb1;
    *(uint4*)&Vts[1][srow][sc8]      = vb0;
    *(uint4*)&Vts[1][srow + 32][sc8] = vb1;
    if (t < 64) kmadd[1][t] = kmb ? 0.f : kNeg;
  };
  auto compute = [&](int buf) {
    f32x4 sc[2][4] = {};
#pragma unroll
    for (int kk = 0; kk < 2; ++kk) {
#pragma unroll
      for (int nf = 0; nf < 4; ++nf) {
        bf16x8 bfr = *(const bf16x8*)&Ks[buf][nf * 16 + l16][kk * 32 + lg * 8];
#pragma unroll
        for (int u = 0; u < 2; ++u)
          sc[u][nf] = __builtin_amdgcn_mfma_f32_16x16x32_bf16(aq[u][kk], bfr, sc[u][nf], 0, 0, 0);
      }
    }
    float madd[4];
#pragma unroll
    for (int nf = 0; nf < 4; ++nf) madd[nf] = kmadd[buf][nf * 16 + l16];
#pragma unroll
    for (int u = 0; u < 2; ++u) {
#pragma unroll
      for (int r = 0; r < 4; ++r) {
        const float p0 = EXP2F(fmaf(sc[u][0][r], kScaleLog2e, madd[0]));
        const float p1 = EXP2F(fmaf(sc[u][1][r], kScaleLog2e, madd[1]));
        const float p2 = EXP2F(fmaf(sc[u][2][r], kScaleLog2e, madd[2]));
        const float p3 = EXP2F(fmaf(sc[u][3][r], kScaleLog2e, madd[3]));
        const int prow = u * 16 + lg * 4 + r;
        uint2 pw;
        pw.x = __builtin_amdgcn_perm(__float_as_uint(p1), __float_as_uint(p0), 0x07060302u);
        pw.y = __builtin_amdgcn_perm(__float_as_uint(p3), __float_as_uint(p2), 0x07060302u);
        *(uint2*)&Ps[w][prow][l16 * 4] = pw;
      }
    }
#pragma unroll
    for (int kk = 0; kk < 2; ++kk) {
      bf16x8 a0 = *(const bf16x8*)&Ps[w][l16][kk * 32 + lg * 8];
      bf16x8 a1 = *(const bf16x8*)&Ps[w][16 + l16][kk * 32 + lg * 8];
#pragma unroll
      for (int nd = 0; nd < 4; ++nd) {
        bf16x8 bfr = *(const bf16x8*)&Vts[buf][nd * 16 + l16][kk * 32 + lg * 8];
        o[0][nd] = __builtin_amdgcn_mfma_f32_16x16x32_bf16(a0, bfr, o[0][nd], 0, 0, 0);
        o[1][nd] = __builtin_amdgcn_mfma_f32_16x16x32_bf16(a1, bfr, o[1][nd], 0, 0, 0);
      }
      lacc[0] = __builtin_amdgcn_mfma_f32_16x16x32_bf16(a0, vone, lacc[0], 0, 0, 0);
      lacc[1] = __builtin_amdgcn_mfma_f32_16x16x32_bf16(a1, vone, lacc[1], 0, 0, 0);
    }
  };

  issueA(0);
  issueB(64);
  for (int i = 0; i < 14; i += 2) {
    WAIT_VMCNT(5);
    writeA();
    issueA((i + 2) * 64);
    __syncthreads();
    compute(0);
    WAIT_VMCNT(5);
    writeB();
    issueB((i + 3) * 64);
    __syncthreads();
    compute(1);
  }
  WAIT_VMCNT(5);
  writeA();
  __syncthreads();
  compute(0);
  WAIT_VMCNT(0);
  writeB();
  __syncthreads();
  compute(1);

#pragma unroll
  for (int u = 0; u < 2; ++u) {
    float rinv[4];
#pragma unroll
    for (int r = 0; r < 4; ++r) rinv[r] = 1.f / lacc[u][r];
#pragma unroll
    for (int nd = 0; nd < 4; ++nd) {
#pragma unroll
      for (int r = 0; r < 4; ++r) {
        const int srowq = q0 + w * 32 + u * 16 + lg * 4 + r;
        y[((size_t)b_ * kS + srowq) * kD + h * kDH + nd * 16 + l16] = o[u][nd][r] * rinv[r];
      }
    }
  }
}

// ---------------------------------------------------------------------------
// Kernel 3: out = LN(qmask*y + q) * gamma + beta, in-place on d_out.
// ---------------------------------------------------------------------------
__global__ __launch_bounds__(256)
void ln_kernel(const float* __restrict__ y, const float* __restrict__ q,
               const int* __restrict__ qmask,
               const float* __restrict__ gamma, const float* __restrict__ beta,
               float* __restrict__ out)
{
  const int w = threadIdx.x >> 6, lane = threadIdx.x & 63;
  const int row = blockIdx.x * 4 + w;
  const int b_ = row >> 10, s = row & 1023;
  const int d0 = lane * 8;
  const int h = d0 >> 6;

  const float* yp = y + (size_t)row * kD + d0;
  const float* qp = q + (size_t)row * kD + d0;
  const int qm = qmask[((b_ * kH + h) % kB) * kS + s];

  float4 y0 = *(const float4*)yp, y1 = *(const float4*)(yp + 4);
  float4 q0 = *(const float4*)qp, q1 = *(const float4*)(qp + 4);
  float vals[8] = { y0.x, y0.y, y0.z, y0.w, y1.x, y1.y, y1.z, y1.w };
  float qs[8]   = { q0.x, q0.y, q0.z, q0.w, q1.x, q1.y, q1.z, q1.w };

  float sum = 0.f, ss = 0.f;
#pragma unroll
  for (int j = 0; j < 8; ++j) {
    const float val = (qm ? vals[j] : 0.f) + qs[j];
    vals[j] = val; sum += val; ss += val * val;
  }
#pragma unroll
  for (int off = 1; off < 64; off <<= 1) {
    sum += __shfl_xor(sum, off);
    ss  += __shfl_xor(ss, off);
  }
  const float mu = sum * (1.f / kD);
  const float var = ss * (1.f / kD) - mu * mu;
  const float rstd = rsqrtf(var + 1e-6f);

  float4 g0 = *(const float4*)(gamma + d0), g1 = *(const float4*)(gamma + d0 + 4);
  float4 be0 = *(const float4*)(beta + d0), be1 = *(const float4*)(beta + d0 + 4);
  float gs[8] = { g0.x, g0.y, g0.z, g0.w, g1.x, g1.y, g1.z, g1.w };
  float bs[8] = { be0.x, be0.y, be0.z, be0.w, be1.x, be1.y, be1.z, be1.w };

  float4 o0, o1;
  o0.x = gs[0] * (vals[0] - mu) * rstd + bs[0];
  o0.y = gs[1] * (vals[1] - mu) * rstd + bs[1];
  o0.z = gs[2] * (vals[2] - mu) * rstd + bs[2];
  o0.w = gs[3] * (vals[3] - mu) * rstd + bs[3];
  o1.x = gs[4] * (vals[4] - mu) * rstd + bs[4];
  o1.y = gs[5] * (vals[5] - mu) * rstd + bs[5];
  o1.z = gs[6] * (vals[6] - mu) * rstd + bs[6];
  o1.w = gs[7] * (vals[7] - mu) * rstd + bs[7];
  *(float4*)(out + (size_t)row * kD + d0) = o0;
  *(float4*)(out + (size_t)row * kD + d0 + 4) = o1;
}

extern "C" void kernel_launch(void* const* d_in, const int* in_sizes, int n_in,
                              void* d_out, int out_size, void* d_ws, size_t ws_size,
                              hipStream_t stream) {
  const float* q  = (const float*)d_in[0];
  const float* k  = (const float*)d_in[1];
  const float* v  = (const float*)d_in[2];
  const int* qmask = (const int*)d_in[3];
  const int* kmask = (const int*)d_in[4];
  const float* Wq = (const float*)d_in[5];
  const float* bq = (const float*)d_in[6];
  const float* Wk = (const float*)d_in[7];
  const float* bk = (const float*)d_in[8];
  const float* Wv = (const float*)d_in[9];
  const float* bv = (const float*)d_in[10];
  const float* gamma = (const float*)d_in[11];
  const float* beta  = (const float*)d_in[12];
  float* out = (float*)d_out;
  unsigned short* wsqkv = (unsigned short*)d_ws;        // 0..24MB: Q,K,V^T bf16
  unsigned short* xbf   = wsqkv + (size_t)3 * 4194304;  // 24..48MB: X bf16
  unsigned short* wbf   = (unsigned short*)d_out;       // d_out scratch for W bf16

  const bool lds_path = ws_size >= (size_t)48 * 1024 * 1024;

  cvt_all<<<1024, 256, 0, stream>>>(q, k, v, Wq, Wk, Wv, xbf, wbf,
                                    lds_path ? 1 : 0);
  if (lds_path) {
    qkv_gemm_lds<<<768, 256, 0, stream>>>(xbf, wbf, bq, bk, bv, wsqkv);
  } else {
    qkv_gemm_reg<<<768, 256, 0, stream>>>(q, k, v, wbf, bq, bk, bv, wsqkv);
  }
  attn_kernel<<<512, 256, 0, stream>>>(wsqkv, kmask, out);
  ln_kernel<<<2048, 256, 0, stream>>>(out, q, qmask, gamma, beta, out);
}

// Round 16
// 70.499 us; speedup vs baseline: 1.1674x; 1.1109x over previous
//
#include <hip/hip_runtime.h>
#include <hip/hip_bf16.h>
#include <stdint.h>

constexpr int kB = 8, kH = 8, kS = 1024, kD = 512, kDH = 64;
constexpr float kNeg = -1e9f;
constexpr float kScaleLog2e = 0.125f * 1.4426950408889634f;

typedef __attribute__((ext_vector_type(8))) short bf16x8;
typedef __attribute__((ext_vector_type(8))) unsigned short u16x8;
typedef __attribute__((ext_vector_type(4))) float f32x4;
typedef __attribute__((ext_vector_type(4))) unsigned short u16x4;

__device__ __forceinline__ unsigned short f2bf(float f) {
  union { float f; unsigned int u; } a; a.f = f;
  return (unsigned short)((a.u + 0x7FFFu + ((a.u >> 16) & 1u)) >> 16);
}
__device__ __forceinline__ float bf2f(unsigned short u) {
  union { unsigned int u; float f; } a; a.u = ((unsigned int)u) << 16;
  return a.f;
}
__device__ __forceinline__ unsigned int pk2bf(float lo, float hi) {
  union { __hip_bfloat162 h; unsigned int u; } cv;
  cv.h = __float22bfloat162_rn(make_float2(lo, hi));
  return cv.u;
}
// Pinned global loads (inline asm: cannot be sunk/CSE'd/re-materialized).
__device__ __forceinline__ uint4 gload16(const void* p) {
  uint4 r;
  asm volatile("global_load_dwordx4 %0, %1, off" : "=v"(r) : "v"(p));
  return r;
}
__device__ __forceinline__ int gload4(const void* p) {
  int r;
  asm volatile("global_load_dword %0, %1, off" : "=v"(r) : "v"(p));
  return r;
}
#define WAIT_VMCNT(N) do { \
  asm volatile("s_waitcnt vmcnt(" #N ")" ::: "memory"); \
  __builtin_amdgcn_sched_barrier(0); } while (0)

__device__ __forceinline__ uint4 cvt4(uint4 a, uint4 b) {
  uint4 r;
  r.x = pk2bf(__uint_as_float(a.x), __uint_as_float(a.y));
  r.y = pk2bf(__uint_as_float(a.z), __uint_as_float(a.w));
  r.z = pk2bf(__uint_as_float(b.x), __uint_as_float(b.y));
  r.w = pk2bf(__uint_as_float(b.z), __uint_as_float(b.w));
  return r;
}

#if __has_builtin(__builtin_amdgcn_exp2f)
#define EXP2F(x) __builtin_amdgcn_exp2f(x)
#else
#define EXP2F(x) exp2f(x)
#endif

// ---------------------------------------------------------------------------
// Kernel 0: W (3x512x512 f32) -> bf16 into d_out (dead scratch until LN).
// ---------------------------------------------------------------------------
__global__ __launch_bounds__(256)
void wcvt_kernel(const float* __restrict__ wq, const float* __restrict__ wk,
                 const float* __restrict__ wv, unsigned short* __restrict__ wout)
{
  const int tid = blockIdx.x * 256 + threadIdx.x;   // 0..196607
  const int z = tid >> 16;
  const int i = (tid & 65535) * 4;
  const float* W = (z == 0) ? wq : (z == 1) ? wk : wv;
  float4 v4 = *(const float4*)(W + i);
  u16x4 pk;
  pk[0] = f2bf(v4.x); pk[1] = f2bf(v4.y); pk[2] = f2bf(v4.z); pk[3] = f2bf(v4.w);
  *(u16x4*)(wout + (size_t)z * 262144 + i) = pk;
}

// ---------------------------------------------------------------------------
// Kernel 1: C = relu(X @ W^T + bias) — R13 verbatim (330 TF: on the measured
// shape-curve ceiling for K=512/N=512-per-z; 8 structural variants R8-R15
// all ~39us). 256 thr 2x2 waves, 128x128 tile, BK=64, 64x64 wave-tile
// acc[4][4], 2-deep pinned prefetch with counted vmcnt(12), LDS dbuf,
// one barrier/step. MFMA operands swapped; packed 8B epilogue stores.
//   Q,K: [b*H+h][s][64]; V: [b*H+h][d][s] with s k-permuted per 64-block.
// ---------------------------------------------------------------------------
__global__ __launch_bounds__(256)
void qkv_gemm_kernel(const float* __restrict__ xq, const float* __restrict__ xk,
                     const float* __restrict__ xv,
                     const unsigned short* __restrict__ wbf,
                     const float* __restrict__ bq, const float* __restrict__ bk,
                     const float* __restrict__ bv,
                     unsigned short* __restrict__ wsout)
{
  __shared__ __align__(16) unsigned short As[2][128][72];
  __shared__ __align__(16) unsigned short Bs[2][128][72];

  const int bid = blockIdx.x;
  const int xcd = bid & 7;
  const int j = bid >> 3;
  const int x = j & 3;
  const int g = (j >> 2) * 8 + xcd;        // 0..191
  const int z = g >> 6;                    // 0..2
  const int y = g & 63;                    // 0..63

  const float* X    = (z == 0) ? xq : (z == 1) ? xk : xv;
  const unsigned short* Wb = wbf + (size_t)z * 262144;
  const float* bias = (z == 0) ? bq : (z == 1) ? bk : bv;
  unsigned short* out = wsout + (size_t)z * (kB * kS * kD);

  const int m0 = y * 128;
  const int n0 = x * 128;
  const int t = threadIdx.x;
  const int lane = t & 63;
  const int w = t >> 6;
  const int wr = w >> 1, wc = w & 1;
  const int l16 = lane & 15, lg = lane >> 4;

  const int row = t >> 3, c8 = (t & 7) * 8;
  const float* Xr = X + (size_t)(m0 + row) * kD + c8;
  const unsigned short* Wr = Wb + (size_t)(n0 + row) * kD + c8;

  f32x4 acc[4][4] = {};
  uint4 pa0, pa1, pa2, pa3, pa4, pa5, pa6, pa7, pb0, pb1, pb2, pb3;
  uint4 qa0, qa1, qa2, qa3, qa4, qa5, qa6, qa7, qb0, qb1, qb2, qb3;

  auto issueP = [&](int kt) {
    pa0 = gload16(Xr + kt);            pa1 = gload16(Xr + kt + 4);
    pa2 = gload16(Xr + 32 * kD + kt);  pa3 = gload16(Xr + 32 * kD + kt + 4);
    pa4 = gload16(Xr + 64 * kD + kt);  pa5 = gload16(Xr + 64 * kD + kt + 4);
    pa6 = gload16(Xr + 96 * kD + kt);  pa7 = gload16(Xr + 96 * kD + kt + 4);
    pb0 = gload16(Wr + kt);            pb1 = gload16(Wr + 32 * kD + kt);
    pb2 = gload16(Wr + 64 * kD + kt);  pb3 = gload16(Wr + 96 * kD + kt);
  };
  auto issueQ = [&](int kt) {
    qa0 = gload16(Xr + kt);            qa1 = gload16(Xr + kt + 4);
    qa2 = gload16(Xr + 32 * kD + kt);  qa3 = gload16(Xr + 32 * kD + kt + 4);
    qa4 = gload16(Xr + 64 * kD + kt);  qa5 = gload16(Xr + 64 * kD + kt + 4);
    qa6 = gload16(Xr + 96 * kD + kt);  qa7 = gload16(Xr + 96 * kD + kt + 4);
    qb0 = gload16(Wr + kt);            qb1 = gload16(Wr + 32 * kD + kt);
    qb2 = gload16(Wr + 64 * kD + kt);  qb3 = gload16(Wr + 96 * kD + kt);
  };
  auto writeP = [&]() {
    *(uint4*)&As[0][row][c8]      = cvt4(pa0, pa1);
    *(uint4*)&As[0][row + 32][c8] = cvt4(pa2, pa3);
    *(uint4*)&As[0][row + 64][c8] = cvt4(pa4, pa5);
    *(uint4*)&As[0][row + 96][c8] = cvt4(pa6, pa7);
    *(uint4*)&Bs[0][row][c8]      = pb0;
    *(uint4*)&Bs[0][row + 32][c8] = pb1;
    *(uint4*)&Bs[0][row + 64][c8] = pb2;
    *(uint4*)&Bs[0][row + 96][c8] = pb3;
  };
  auto writeQ = [&]() {
    *(uint4*)&As[1][row][c8]      = cvt4(qa0, qa1);
    *(uint4*)&As[1][row + 32][c8] = cvt4(qa2, qa3);
    *(uint4*)&As[1][row + 64][c8] = cvt4(qa4, qa5);
    *(uint4*)&As[1][row + 96][c8] = cvt4(qa6, qa7);
    *(uint4*)&Bs[1][row][c8]      = qb0;
    *(uint4*)&Bs[1][row + 32][c8] = qb1;
    *(uint4*)&Bs[1][row + 64][c8] = qb2;
    *(uint4*)&Bs[1][row + 96][c8] = qb3;
  };
  auto mfma_phase = [&](int buf) {
#pragma unroll
    for (int kk = 0; kk < 2; ++kk) {
      bf16x8 av[4], bv[4];
#pragma unroll
      for (int mf = 0; mf < 4; ++mf)
        av[mf] = *(const bf16x8*)&As[buf][wr * 64 + mf * 16 + l16][kk * 32 + lg * 8];
#pragma unroll
      for (int nf = 0; nf < 4; ++nf)
        bv[nf] = *(const bf16x8*)&Bs[buf][wc * 64 + nf * 16 + l16][kk * 32 + lg * 8];
#pragma unroll
      for (int nf = 0; nf < 4; ++nf)
#pragma unroll
        for (int mf = 0; mf < 4; ++mf)
          acc[mf][nf] = __builtin_amdgcn_mfma_f32_16x16x32_bf16(bv[nf], av[mf], acc[mf][nf], 0, 0, 0);
    }
  };

  issueP(0);
  issueQ(64);
#pragma unroll
  for (int i = 0; i < 6; i += 2) {
    WAIT_VMCNT(12);
    writeP();
    issueP((i + 2) * 64);
    __syncthreads();
    mfma_phase(0);
    WAIT_VMCNT(12);
    writeQ();
    issueQ((i + 3) * 64);
    __syncthreads();
    mfma_phase(1);
  }
  WAIT_VMCNT(12);
  writeP();
  __syncthreads();
  mfma_phase(0);
  WAIT_VMCNT(0);
  writeQ();
  __syncthreads();
  mfma_phase(1);

  if (z == 2) {
    const int mmbase = m0 + wr * 64;
    const int b_ = mmbase >> 10, sbase = mmbase & 1023;
#pragma unroll
    for (int nf = 0; nf < 4; ++nf) {
#pragma unroll
      for (int r = 0; r < 4; ++r) {
        const int n = n0 + wc * 64 + nf * 16 + lg * 4 + r;
        const float bval = bias[n];
        const int h = n >> 6, dd = n & 63;
        u16x4 pk;
#pragma unroll
        for (int mf = 0; mf < 4; ++mf) {
          float vv = acc[mf][nf][r] + bval;
          vv = vv > 0.f ? vv : 0.f;
          pk[mf] = f2bf(vv);
        }
        *(u16x4*)&out[((size_t)((b_ * kH + h) * kDH + dd)) * kS + sbase + l16 * 4] = pk;
      }
    }
  } else {
#pragma unroll
    for (int mf = 0; mf < 4; ++mf) {
      const int mm = m0 + wr * 64 + mf * 16 + l16;
      const int b_ = mm >> 10, s = mm & 1023;
#pragma unroll
      for (int nf = 0; nf < 4; ++nf) {
        const int nbase = n0 + wc * 64 + nf * 16 + lg * 4;
        const int h = nbase >> 6, dd = nbase & 63;
        u16x4 pk;
#pragma unroll
        for (int r = 0; r < 4; ++r) {
          float vv = acc[mf][nf][r] + bias[nbase + r];
          vv = vv > 0.f ? vv : 0.f;
          pk[r] = f2bf(vv);
        }
        *(u16x4*)&out[((size_t)(b_ * kH + h) * kS + s) * kDH + dd] = pk;
      }
    }
  }
}

// ---------------------------------------------------------------------------
// Kernel 2: flash attention (R13 structure) + T5 s_setprio around both MFMA
// clusters (catalog: +4-7% on attn), and y written as BF16 to workspace
// (halves attn write + LN read traffic; |y|<~4 so bf16 rounding adds <0.01
// to absmax). 512 blocks (bh x 8 q-tiles of 128 rows), 4 waves x 32 q-rows;
// 2-deep pinned prefetch, counted vmcnt(5); LDS dbuf, one barrier/step.
// ---------------------------------------------------------------------------
__global__ __launch_bounds__(256)
void attn_kernel(const unsigned short* __restrict__ ws,
                 const int* __restrict__ key_mask,
                 unsigned short* __restrict__ ybf)
{
  __shared__ __align__(16) unsigned short Ks[2][64][72];
  __shared__ __align__(16) unsigned short Vts[2][64][72];
  __shared__ __align__(16) unsigned short Ps[4][32][72];
  __shared__ float kmadd[2][64];

  const unsigned short* Qw = ws;
  const unsigned short* Kw = ws + (size_t)1 * kB * kS * kD;
  const unsigned short* Vw = ws + (size_t)2 * kB * kS * kD;

  const int bid = blockIdx.x;
  const int xcd = bid & 7;
  const int j = bid >> 3;
  const int qx = j & 7;
  const int bh = (j >> 3) * 8 + xcd;

  const int q0 = qx * 128;
  const int t = threadIdx.x;
  const int w = t >> 6, lane = t & 63;
  const int l16 = lane & 15, lg = lane >> 4;
  const int b_ = bh / kH, h = bh % kH;

  const unsigned short* Qb = Qw + ((size_t)bh * kS + q0) * kDH;
  const unsigned short* Kb = Kw + (size_t)bh * kS * kDH;
  const unsigned short* Vb = Vw + (size_t)bh * kDH * kS;
  const int* km = key_mask + (bh % kB) * kS;

  const int srow = t >> 3, sc8 = (t & 7) * 8;
  const unsigned short* KbR0 = Kb + (size_t)srow * kDH + sc8;
  const unsigned short* KbR1 = Kb + (size_t)(srow + 32) * kDH + sc8;
  const unsigned short* VbR0 = Vb + (size_t)srow * kS + sc8;
  const unsigned short* VbR1 = Vb + (size_t)(srow + 32) * kS + sc8;

  bf16x8 aq[2][2];
#pragma unroll
  for (int u = 0; u < 2; ++u)
#pragma unroll
    for (int kk = 0; kk < 2; ++kk)
      aq[u][kk] = *(const bf16x8*)(Qb + (size_t)(w * 32 + u * 16 + l16) * kDH + kk * 32 + lg * 8);

  bf16x8 vone;
#pragma unroll
  for (int jj = 0; jj < 8; ++jj) vone[jj] = (short)0x3F80;

  f32x4 o[2][4] = {};
  f32x4 lacc[2] = {};

  uint4 ka0, ka1, va0, va1; int kma;
  uint4 kb0, kb1, vb0, vb1; int kmb;

  auto issueA = [&](int kv0) {
    ka0 = gload16(KbR0 + (size_t)kv0 * kDH);
    ka1 = gload16(KbR1 + (size_t)kv0 * kDH);
    va0 = gload16(VbR0 + kv0);
    va1 = gload16(VbR1 + kv0);
    kma = gload4(km + kv0 + (t & 63));
  };
  auto issueB = [&](int kv0) {
    kb0 = gload16(KbR0 + (size_t)kv0 * kDH);
    kb1 = gload16(KbR1 + (size_t)kv0 * kDH);
    vb0 = gload16(VbR0 + kv0);
    vb1 = gload16(VbR1 + kv0);
    kmb = gload4(km + kv0 + (t & 63));
  };
  auto writeA = [&]() {
    *(uint4*)&Ks[0][srow][sc8]       = ka0;
    *(uint4*)&Ks[0][srow + 32][sc8]  = ka1;
    *(uint4*)&Vts[0][srow][sc8]      = va0;
    *(uint4*)&Vts[0][srow + 32][sc8] = va1;
    if (t < 64) kmadd[0][t] = kma ? 0.f : kNeg;
  };
  auto writeB = [&]() {
    *(uint4*)&Ks[1][srow][sc8]       = kb0;
    *(uint4*)&Ks[1][srow + 32][sc8]  = kb1;
    *(uint4*)&Vts[1][srow][sc8]      = vb0;
    *(uint4*)&Vts[1][srow + 32][sc8] = vb1;
    if (t < 64) kmadd[1][t] = kmb ? 0.f : kNeg;
  };
  auto compute = [&](int buf) {
    f32x4 sc[2][4] = {};
    __builtin_amdgcn_s_setprio(1);
#pragma unroll
    for (int kk = 0; kk < 2; ++kk) {
#pragma unroll
      for (int nf = 0; nf < 4; ++nf) {
        bf16x8 bfr = *(const bf16x8*)&Ks[buf][nf * 16 + l16][kk * 32 + lg * 8];
#pragma unroll
        for (int u = 0; u < 2; ++u)
          sc[u][nf] = __builtin_amdgcn_mfma_f32_16x16x32_bf16(aq[u][kk], bfr, sc[u][nf], 0, 0, 0);
      }
    }
    __builtin_amdgcn_s_setprio(0);
    float madd[4];
#pragma unroll
    for (int nf = 0; nf < 4; ++nf) madd[nf] = kmadd[buf][nf * 16 + l16];
#pragma unroll
    for (int u = 0; u < 2; ++u) {
#pragma unroll
      for (int r = 0; r < 4; ++r) {
        const float p0 = EXP2F(fmaf(sc[u][0][r], kScaleLog2e, madd[0]));
        const float p1 = EXP2F(fmaf(sc[u][1][r], kScaleLog2e, madd[1]));
        const float p2 = EXP2F(fmaf(sc[u][2][r], kScaleLog2e, madd[2]));
        const float p3 = EXP2F(fmaf(sc[u][3][r], kScaleLog2e, madd[3]));
        const int prow = u * 16 + lg * 4 + r;
        uint2 pw;
        pw.x = __builtin_amdgcn_perm(__float_as_uint(p1), __float_as_uint(p0), 0x07060302u);
        pw.y = __builtin_amdgcn_perm(__float_as_uint(p3), __float_as_uint(p2), 0x07060302u);
        *(uint2*)&Ps[w][prow][l16 * 4] = pw;
      }
    }
    __builtin_amdgcn_s_setprio(1);
#pragma unroll
    for (int kk = 0; kk < 2; ++kk) {
      bf16x8 a0 = *(const bf16x8*)&Ps[w][l16][kk * 32 + lg * 8];
      bf16x8 a1 = *(const bf16x8*)&Ps[w][16 + l16][kk * 32 + lg * 8];
#pragma unroll
      for (int nd = 0; nd < 4; ++nd) {
        bf16x8 bfr = *(const bf16x8*)&Vts[buf][nd * 16 + l16][kk * 32 + lg * 8];
        o[0][nd] = __builtin_amdgcn_mfma_f32_16x16x32_bf16(a0, bfr, o[0][nd], 0, 0, 0);
        o[1][nd] = __builtin_amdgcn_mfma_f32_16x16x32_bf16(a1, bfr, o[1][nd], 0, 0, 0);
      }
      lacc[0] = __builtin_amdgcn_mfma_f32_16x16x32_bf16(a0, vone, lacc[0], 0, 0, 0);
      lacc[1] = __builtin_amdgcn_mfma_f32_16x16x32_bf16(a1, vone, lacc[1], 0, 0, 0);
    }
    __builtin_amdgcn_s_setprio(0);
  };

  issueA(0);
  issueB(64);
  for (int i = 0; i < 14; i += 2) {
    WAIT_VMCNT(5);
    writeA();
    issueA((i + 2) * 64);
    __syncthreads();
    compute(0);
    WAIT_VMCNT(5);
    writeB();
    issueB((i + 3) * 64);
    __syncthreads();
    compute(1);
  }
  WAIT_VMCNT(5);
  writeA();
  __syncthreads();
  compute(0);
  WAIT_VMCNT(0);
  writeB();
  __syncthreads();
  compute(1);

  // epilogue: divide by l, write y as BF16 into [b][s][512] layout
#pragma unroll
  for (int u = 0; u < 2; ++u) {
    float rinv[4];
#pragma unroll
    for (int r = 0; r < 4; ++r) rinv[r] = 1.f / lacc[u][r];
#pragma unroll
    for (int nd = 0; nd < 4; ++nd) {
#pragma unroll
      for (int r = 0; r < 4; ++r) {
        const int srowq = q0 + w * 32 + u * 16 + lg * 4 + r;
        ybf[((size_t)b_ * kS + srowq) * kD + h * kDH + nd * 16 + l16] =
            f2bf(o[u][nd][r] * rinv[r]);
      }
    }
  }
}

// ---------------------------------------------------------------------------
// Kernel 3: out = LN(qmask*y + q) * gamma + beta. y read as bf16 from ws.
// One wave per row; qmask row = ((b*H + h) % B)  (reference quirk).
// ---------------------------------------------------------------------------
__global__ __launch_bounds__(256)
void ln_kernel(const unsigned short* __restrict__ ybf, const float* __restrict__ q,
               const int* __restrict__ qmask,
               const float* __restrict__ gamma, const float* __restrict__ beta,
               float* __restrict__ out)
{
  const int w = threadIdx.x >> 6, lane = threadIdx.x & 63;
  const int row = blockIdx.x * 4 + w;            // 0..8191
  const int b_ = row >> 10, s = row & 1023;
  const int d0 = lane * 8;
  const int h = d0 >> 6;

  const unsigned short* yp = ybf + (size_t)row * kD + d0;
  const float* qp = q + (size_t)row * kD + d0;
  const int qm = qmask[((b_ * kH + h) % kB) * kS + s];

  u16x8 yv = *(const u16x8*)yp;
  float4 q0 = *(const float4*)qp, q1 = *(const float4*)(qp + 4);
  float vals[8];
#pragma unroll
  for (int jj = 0; jj < 8; ++jj) vals[jj] = bf2f(yv[jj]);
  float qs[8]   = { q0.x, q0.y, q0.z, q0.w, q1.x, q1.y, q1.z, q1.w };

  float sum = 0.f, ss = 0.f;
#pragma unroll
  for (int jj = 0; jj < 8; ++jj) {
    const float val = (qm ? vals[jj] : 0.f) + qs[jj];
    vals[jj] = val; sum += val; ss += val * val;
  }
#pragma unroll
  for (int off = 1; off < 64; off <<= 1) {
    sum += __shfl_xor(sum, off);
    ss  += __shfl_xor(ss, off);
  }
  const float mu = sum * (1.f / kD);
  const float var = ss * (1.f / kD) - mu * mu;
  const float rstd = rsqrtf(var + 1e-6f);

  float4 g0 = *(const float4*)(gamma + d0), g1 = *(const float4*)(gamma + d0 + 4);
  float4 be0 = *(const float4*)(beta + d0), be1 = *(const float4*)(beta + d0 + 4);
  float gs[8] = { g0.x, g0.y, g0.z, g0.w, g1.x, g1.y, g1.z, g1.w };
  float bs[8] = { be0.x, be0.y, be0.z, be0.w, be1.x, be1.y, be1.z, be1.w };

  float4 o0, o1;
  o0.x = gs[0] * (vals[0] - mu) * rstd + bs[0];
  o0.y = gs[1] * (vals[1] - mu) * rstd + bs[1];
  o0.z = gs[2] * (vals[2] - mu) * rstd + bs[2];
  o0.w = gs[3] * (vals[3] - mu) * rstd + bs[3];
  o1.x = gs[4] * (vals[4] - mu) * rstd + bs[4];
  o1.y = gs[5] * (vals[5] - mu) * rstd + bs[5];
  o1.z = gs[6] * (vals[6] - mu) * rstd + bs[6];
  o1.w = gs[7] * (vals[7] - mu) * rstd + bs[7];
  *(float4*)(out + (size_t)row * kD + d0) = o0;
  *(float4*)(out + (size_t)row * kD + d0 + 4) = o1;
}

extern "C" void kernel_launch(void* const* d_in, const int* in_sizes, int n_in,
                              void* d_out, int out_size, void* d_ws, size_t ws_size,
                              hipStream_t stream) {
  const float* q  = (const float*)d_in[0];
  const float* k  = (const float*)d_in[1];
  const float* v  = (const float*)d_in[2];
  const int* qmask = (const int*)d_in[3];
  const int* kmask = (const int*)d_in[4];
  const float* Wq = (const float*)d_in[5];
  const float* bq = (const float*)d_in[6];
  const float* Wk = (const float*)d_in[7];
  const float* bk = (const float*)d_in[8];
  const float* Wv = (const float*)d_in[9];
  const float* bv = (const float*)d_in[10];
  const float* gamma = (const float*)d_in[11];
  const float* beta  = (const float*)d_in[12];
  float* out = (float*)d_out;
  unsigned short* wsqkv = (unsigned short*)d_ws;        // 0..24MB: Q,K,V^T bf16
  unsigned short* ybf   = wsqkv + (size_t)3 * 4194304;  // 24..32.4MB: y bf16
  unsigned short* wbf   = (unsigned short*)d_out;       // d_out scratch for W bf16

  wcvt_kernel<<<768, 256, 0, stream>>>(Wq, Wk, Wv, wbf);
  qkv_gemm_kernel<<<768, 256, 0, stream>>>(
      q, k, v, wbf, bq, bk, bv, wsqkv);
  attn_kernel<<<512, 256, 0, stream>>>(wsqkv, kmask, ybf);
  ln_kernel<<<2048, 256, 0, stream>>>(ybf, q, qmask, gamma, beta, out);
}

// Round 17
// 68.955 us; speedup vs baseline: 1.1936x; 1.0224x over previous
//
#include <hip/hip_runtime.h>
#include <hip/hip_bf16.h>
#include <stdint.h>

constexpr int kB = 8, kH = 8, kS = 1024, kD = 512, kDH = 64;
constexpr float kNeg = -1e9f;
constexpr float kScaleLog2e = 0.125f * 1.4426950408889634f;

typedef __attribute__((ext_vector_type(8))) short bf16x8;
typedef __attribute__((ext_vector_type(8))) unsigned short u16x8;
typedef __attribute__((ext_vector_type(4))) float f32x4;
typedef __attribute__((ext_vector_type(4))) unsigned short u16x4;

__device__ __forceinline__ unsigned short f2bf(float f) {
  union { float f; unsigned int u; } a; a.f = f;
  return (unsigned short)((a.u + 0x7FFFu + ((a.u >> 16) & 1u)) >> 16);
}
__device__ __forceinline__ float bf2f(unsigned short u) {
  union { unsigned int u; float f; } a; a.u = ((unsigned int)u) << 16;
  return a.f;
}
__device__ __forceinline__ unsigned int pk2bf(float lo, float hi) {
  union { __hip_bfloat162 h; unsigned int u; } cv;
  cv.h = __float22bfloat162_rn(make_float2(lo, hi));
  return cv.u;
}
// Pinned global loads (inline asm: cannot be sunk/CSE'd/re-materialized).
__device__ __forceinline__ uint4 gload16(const void* p) {
  uint4 r;
  asm volatile("global_load_dwordx4 %0, %1, off" : "=v"(r) : "v"(p));
  return r;
}
__device__ __forceinline__ int gload4(const void* p) {
  int r;
  asm volatile("global_load_dword %0, %1, off" : "=v"(r) : "v"(p));
  return r;
}
#define WAIT_VMCNT(N) do { \
  asm volatile("s_waitcnt vmcnt(" #N ")" ::: "memory"); \
  __builtin_amdgcn_sched_barrier(0); } while (0)

__device__ __forceinline__ uint4 cvt4(uint4 a, uint4 b) {
  uint4 r;
  r.x = pk2bf(__uint_as_float(a.x), __uint_as_float(a.y));
  r.y = pk2bf(__uint_as_float(a.z), __uint_as_float(a.w));
  r.z = pk2bf(__uint_as_float(b.x), __uint_as_float(b.y));
  r.w = pk2bf(__uint_as_float(b.z), __uint_as_float(b.w));
  return r;
}

#if __has_builtin(__builtin_amdgcn_exp2f)
#define EXP2F(x) __builtin_amdgcn_exp2f(x)
#else
#define EXP2F(x) exp2f(x)
#endif

// ---------------------------------------------------------------------------
// Kernel 0: W (3x512x512 f32) -> bf16 into d_out (dead scratch until LN).
// ---------------------------------------------------------------------------
__global__ __launch_bounds__(256)
void wcvt_kernel(const float* __restrict__ wq, const float* __restrict__ wk,
                 const float* __restrict__ wv, unsigned short* __restrict__ wout)
{
  const int tid = blockIdx.x * 256 + threadIdx.x;   // 0..196607
  const int z = tid >> 16;
  const int i = (tid & 65535) * 4;
  const float* W = (z == 0) ? wq : (z == 1) ? wk : wv;
  float4 v4 = *(const float4*)(W + i);
  u16x4 pk;
  pk[0] = f2bf(v4.x); pk[1] = f2bf(v4.y); pk[2] = f2bf(v4.z); pk[3] = f2bf(v4.w);
  *(u16x4*)(wout + (size_t)z * 262144 + i) = pk;
}

// ---------------------------------------------------------------------------
// Kernel 1: C = relu(X @ W^T + bias). R13 math/layout/epilogue + PHASE-SPLIT
// schedule (T3-lite + T5): each K-step's compute is 4 phases (kk-half x
// nf-pair), each = {ds_read its fragments; issue 3 of the 12 next-tile
// pinned loads; setprio(1); 8 MFMA; setprio(0); barrier}. Counted vmcnt(12)
// 2-deep prefetch unchanged. Mechanism: m233 (2-barrier lockstep = ~72%
// stage+bar overhead), m196/m218b (phase-split + setprio pays together).
//   Q,K: [b*H+h][s][64]; V: [b*H+h][d][s] with s k-permuted per 64-block.
// ---------------------------------------------------------------------------
__global__ __launch_bounds__(256)
void qkv_gemm_kernel(const float* __restrict__ xq, const float* __restrict__ xk,
                     const float* __restrict__ xv,
                     const unsigned short* __restrict__ wbf,
                     const float* __restrict__ bq, const float* __restrict__ bk,
                     const float* __restrict__ bv,
                     unsigned short* __restrict__ wsout)
{
  __shared__ __align__(16) unsigned short As[2][128][72];
  __shared__ __align__(16) unsigned short Bs[2][128][72];

  const int bid = blockIdx.x;
  const int xcd = bid & 7;
  const int j = bid >> 3;
  const int x = j & 3;
  const int g = (j >> 2) * 8 + xcd;        // 0..191
  const int z = g >> 6;                    // 0..2
  const int y = g & 63;                    // 0..63

  const float* X    = (z == 0) ? xq : (z == 1) ? xk : xv;
  const unsigned short* Wb = wbf + (size_t)z * 262144;
  const float* bias = (z == 0) ? bq : (z == 1) ? bk : bv;
  unsigned short* out = wsout + (size_t)z * (kB * kS * kD);

  const int m0 = y * 128;
  const int n0 = x * 128;
  const int t = threadIdx.x;
  const int lane = t & 63;
  const int w = t >> 6;
  const int wr = w >> 1, wc = w & 1;
  const int l16 = lane & 15, lg = lane >> 4;

  const int row = t >> 3, c8 = (t & 7) * 8;
  const float* Xr = X + (size_t)(m0 + row) * kD + c8;
  const unsigned short* Wr = Wb + (size_t)(n0 + row) * kD + c8;

  f32x4 acc[4][4] = {};
  uint4 pa0, pa1, pa2, pa3, pa4, pa5, pa6, pa7, pb0, pb1, pb2, pb3;
  uint4 qa0, qa1, qa2, qa3, qa4, qa5, qa6, qa7, qb0, qb1, qb2, qb3;

  // full issues (prologue)
  auto issueP = [&](int kt) {
    pa0 = gload16(Xr + kt);            pa1 = gload16(Xr + kt + 4);
    pa2 = gload16(Xr + 32 * kD + kt);  pa3 = gload16(Xr + 32 * kD + kt + 4);
    pa4 = gload16(Xr + 64 * kD + kt);  pa5 = gload16(Xr + 64 * kD + kt + 4);
    pa6 = gload16(Xr + 96 * kD + kt);  pa7 = gload16(Xr + 96 * kD + kt + 4);
    pb0 = gload16(Wr + kt);            pb1 = gload16(Wr + 32 * kD + kt);
    pb2 = gload16(Wr + 64 * kD + kt);  pb3 = gload16(Wr + 96 * kD + kt);
  };
  auto issueQ = [&](int kt) {
    qa0 = gload16(Xr + kt);            qa1 = gload16(Xr + kt + 4);
    qa2 = gload16(Xr + 32 * kD + kt);  qa3 = gload16(Xr + 32 * kD + kt + 4);
    qa4 = gload16(Xr + 64 * kD + kt);  qa5 = gload16(Xr + 64 * kD + kt + 4);
    qa6 = gload16(Xr + 96 * kD + kt);  qa7 = gload16(Xr + 96 * kD + kt + 4);
    qb0 = gload16(Wr + kt);            qb1 = gload16(Wr + 32 * kD + kt);
    qb2 = gload16(Wr + 64 * kD + kt);  qb3 = gload16(Wr + 96 * kD + kt);
  };
  // quarter issues (interleaved into compute phases)
  auto issueP1 = [&](int kt) {
    pa0 = gload16(Xr + kt);            pa1 = gload16(Xr + kt + 4);
    pa2 = gload16(Xr + 32 * kD + kt);
  };
  auto issueP2 = [&](int kt) {
    pa3 = gload16(Xr + 32 * kD + kt + 4);
    pa4 = gload16(Xr + 64 * kD + kt);  pa5 = gload16(Xr + 64 * kD + kt + 4);
  };
  auto issueP3 = [&](int kt) {
    pa6 = gload16(Xr + 96 * kD + kt);  pa7 = gload16(Xr + 96 * kD + kt + 4);
    pb0 = gload16(Wr + kt);
  };
  auto issueP4 = [&](int kt) {
    pb1 = gload16(Wr + 32 * kD + kt);
    pb2 = gload16(Wr + 64 * kD + kt);  pb3 = gload16(Wr + 96 * kD + kt);
  };
  auto issueQ1 = [&](int kt) {
    qa0 = gload16(Xr + kt);            qa1 = gload16(Xr + kt + 4);
    qa2 = gload16(Xr + 32 * kD + kt);
  };
  auto issueQ2 = [&](int kt) {
    qa3 = gload16(Xr + 32 * kD + kt + 4);
    qa4 = gload16(Xr + 64 * kD + kt);  qa5 = gload16(Xr + 64 * kD + kt + 4);
  };
  auto issueQ3 = [&](int kt) {
    qa6 = gload16(Xr + 96 * kD + kt);  qa7 = gload16(Xr + 96 * kD + kt + 4);
    qb0 = gload16(Wr + kt);
  };
  auto issueQ4 = [&](int kt) {
    qb1 = gload16(Wr + 32 * kD + kt);
    qb2 = gload16(Wr + 64 * kD + kt);  qb3 = gload16(Wr + 96 * kD + kt);
  };
  auto writeP = [&]() {
    *(uint4*)&As[0][row][c8]      = cvt4(pa0, pa1);
    *(uint4*)&As[0][row + 32][c8] = cvt4(pa2, pa3);
    *(uint4*)&As[0][row + 64][c8] = cvt4(pa4, pa5);
    *(uint4*)&As[0][row + 96][c8] = cvt4(pa6, pa7);
    *(uint4*)&Bs[0][row][c8]      = pb0;
    *(uint4*)&Bs[0][row + 32][c8] = pb1;
    *(uint4*)&Bs[0][row + 64][c8] = pb2;
    *(uint4*)&Bs[0][row + 96][c8] = pb3;
  };
  auto writeQ = [&]() {
    *(uint4*)&As[1][row][c8]      = cvt4(qa0, qa1);
    *(uint4*)&As[1][row + 32][c8] = cvt4(qa2, qa3);
    *(uint4*)&As[1][row + 64][c8] = cvt4(qa4, qa5);
    *(uint4*)&As[1][row + 96][c8] = cvt4(qa6, qa7);
    *(uint4*)&Bs[1][row][c8]      = qb0;
    *(uint4*)&Bs[1][row + 32][c8] = qb1;
    *(uint4*)&Bs[1][row + 64][c8] = qb2;
    *(uint4*)&Bs[1][row + 96][c8] = qb3;
  };

  // 4-phase compute on LDS buffer BUF; optionally interleaves the quarter
  // issues I1..I4 for the NEXT tile of the opposite register set.
#define COMPUTE_PHASED(BUF, KT, I1, I2, I3, I4)                               \
  do {                                                                        \
    bf16x8 av0, av1, av2, av3, bv0, bv1;                                      \
    /* phase 1: kk=0, nf=0,1 */                                               \
    av0 = *(const bf16x8*)&As[BUF][wr * 64 +  0 + l16][lg * 8];               \
    av1 = *(const bf16x8*)&As[BUF][wr * 64 + 16 + l16][lg * 8];               \
    av2 = *(const bf16x8*)&As[BUF][wr * 64 + 32 + l16][lg * 8];               \
    av3 = *(const bf16x8*)&As[BUF][wr * 64 + 48 + l16][lg * 8];               \
    bv0 = *(const bf16x8*)&Bs[BUF][wc * 64 +  0 + l16][lg * 8];               \
    bv1 = *(const bf16x8*)&Bs[BUF][wc * 64 + 16 + l16][lg * 8];               \
    if (KT >= 0) I1(KT);                                                      \
    __builtin_amdgcn_s_setprio(1);                                            \
    acc[0][0] = __builtin_amdgcn_mfma_f32_16x16x32_bf16(bv0, av0, acc[0][0], 0, 0, 0); \
    acc[1][0] = __builtin_amdgcn_mfma_f32_16x16x32_bf16(bv0, av1, acc[1][0], 0, 0, 0); \
    acc[2][0] = __builtin_amdgcn_mfma_f32_16x16x32_bf16(bv0, av2, acc[2][0], 0, 0, 0); \
    acc[3][0] = __builtin_amdgcn_mfma_f32_16x16x32_bf16(bv0, av3, acc[3][0], 0, 0, 0); \
    acc[0][1] = __builtin_amdgcn_mfma_f32_16x16x32_bf16(bv1, av0, acc[0][1], 0, 0, 0); \
    acc[1][1] = __builtin_amdgcn_mfma_f32_16x16x32_bf16(bv1, av1, acc[1][1], 0, 0, 0); \
    acc[2][1] = __builtin_amdgcn_mfma_f32_16x16x32_bf16(bv1, av2, acc[2][1], 0, 0, 0); \
    acc[3][1] = __builtin_amdgcn_mfma_f32_16x16x32_bf16(bv1, av3, acc[3][1], 0, 0, 0); \
    __builtin_amdgcn_s_setprio(0);                                            \
    __syncthreads();                                                          \
    /* phase 2: kk=0, nf=2,3 */                                               \
    bv0 = *(const bf16x8*)&Bs[BUF][wc * 64 + 32 + l16][lg * 8];               \
    bv1 = *(const bf16x8*)&Bs[BUF][wc * 64 + 48 + l16][lg * 8];               \
    if (KT >= 0) I2(KT);                                                      \
    __builtin_amdgcn_s_setprio(1);                                            \
    acc[0][2] = __builtin_amdgcn_mfma_f32_16x16x32_bf16(bv0, av0, acc[0][2], 0, 0, 0); \
    acc[1][2] = __builtin_amdgcn_mfma_f32_16x16x32_bf16(bv0, av1, acc[1][2], 0, 0, 0); \
    acc[2][2] = __builtin_amdgcn_mfma_f32_16x16x32_bf16(bv0, av2, acc[2][2], 0, 0, 0); \
    acc[3][2] = __builtin_amdgcn_mfma_f32_16x16x32_bf16(bv0, av3, acc[3][2], 0, 0, 0); \
    acc[0][3] = __builtin_amdgcn_mfma_f32_16x16x32_bf16(bv1, av0, acc[0][3], 0, 0, 0); \
    acc[1][3] = __builtin_amdgcn_mfma_f32_16x16x32_bf16(bv1, av1, acc[1][3], 0, 0, 0); \
    acc[2][3] = __builtin_amdgcn_mfma_f32_16x16x32_bf16(bv1, av2, acc[2][3], 0, 0, 0); \
    acc[3][3] = __builtin_amdgcn_mfma_f32_16x16x32_bf16(bv1, av3, acc[3][3], 0, 0, 0); \
    __builtin_amdgcn_s_setprio(0);                                            \
    __syncthreads();                                                          \
    /* phase 3: kk=1, nf=0,1 */                                               \
    av0 = *(const bf16x8*)&As[BUF][wr * 64 +  0 + l16][32 + lg * 8];          \
    av1 = *(const bf16x8*)&As[BUF][wr * 64 + 16 + l16][32 + lg * 8];          \
    av2 = *(const bf16x8*)&As[BUF][wr * 64 + 32 + l16][32 + lg * 8];          \
    av3 = *(const bf16x8*)&As[BUF][wr * 64 + 48 + l16][32 + lg * 8];          \
    bv0 = *(const bf16x8*)&Bs[BUF][wc * 64 +  0 + l16][32 + lg * 8];          \
    bv1 = *(const bf16x8*)&Bs[BUF][wc * 64 + 16 + l16][32 + lg * 8];          \
    if (KT >= 0) I3(KT);                                                      \
    __builtin_amdgcn_s_setprio(1);                                            \
    acc[0][0] = __builtin_amdgcn_mfma_f32_16x16x32_bf16(bv0, av0, acc[0][0], 0, 0, 0); \
    acc[1][0] = __builtin_amdgcn_mfma_f32_16x16x32_bf16(bv0, av1, acc[1][0], 0, 0, 0); \
    acc[2][0] = __builtin_amdgcn_mfma_f32_16x16x32_bf16(bv0, av2, acc[2][0], 0, 0, 0); \
    acc[3][0] = __builtin_amdgcn_mfma_f32_16x16x32_bf16(bv0, av3, acc[3][0], 0, 0, 0); \
    acc[0][1] = __builtin_amdgcn_mfma_f32_16x16x32_bf16(bv1, av0, acc[0][1], 0, 0, 0); \
    acc[1][1] = __builtin_amdgcn_mfma_f32_16x16x32_bf16(bv1, av1, acc[1][1], 0, 0, 0); \
    acc[2][1] = __builtin_amdgcn_mfma_f32_16x16x32_bf16(bv1, av2, acc[2][1], 0, 0, 0); \
    acc[3][1] = __builtin_amdgcn_mfma_f32_16x16x32_bf16(bv1, av3, acc[3][1], 0, 0, 0); \
    __builtin_amdgcn_s_setprio(0);                                            \
    __syncthreads();                                                          \
    /* phase 4: kk=1, nf=2,3 */                                               \
    bv0 = *(const bf16x8*)&Bs[BUF][wc * 64 + 32 + l16][32 + lg * 8];          \
    bv1 = *(const bf16x8*)&Bs[BUF][wc * 64 + 48 + l16][32 + lg * 8];          \
    if (KT >= 0) I4(KT);                                                      \
    __builtin_amdgcn_s_setprio(1);                                            \
    acc[0][2] = __builtin_amdgcn_mfma_f32_16x16x32_bf16(bv0, av0, acc[0][2], 0, 0, 0); \
    acc[1][2] = __builtin_amdgcn_mfma_f32_16x16x32_bf16(bv0, av1, acc[1][2], 0, 0, 0); \
    acc[2][2] = __builtin_amdgcn_mfma_f32_16x16x32_bf16(bv0, av2, acc[2][2], 0, 0, 0); \
    acc[3][2] = __builtin_amdgcn_mfma_f32_16x16x32_bf16(bv0, av3, acc[3][2], 0, 0, 0); \
    acc[0][3] = __builtin_amdgcn_mfma_f32_16x16x32_bf16(bv1, av0, acc[0][3], 0, 0, 0); \
    acc[1][3] = __builtin_amdgcn_mfma_f32_16x16x32_bf16(bv1, av1, acc[1][3], 0, 0, 0); \
    acc[2][3] = __builtin_amdgcn_mfma_f32_16x16x32_bf16(bv1, av2, acc[2][3], 0, 0, 0); \
    acc[3][3] = __builtin_amdgcn_mfma_f32_16x16x32_bf16(bv1, av3, acc[3][3], 0, 0, 0); \
    __builtin_amdgcn_s_setprio(0);                                            \
  } while (0)

  issueP(0);
  issueQ(64);
#pragma unroll
  for (int i = 0; i < 6; i += 2) {
    WAIT_VMCNT(12);                 // set P (tile i) landed; Q still flying
    writeP();
    __syncthreads();
    COMPUTE_PHASED(0, (i + 2) * 64, issueP1, issueP2, issueP3, issueP4);
    WAIT_VMCNT(12);                 // set Q (tile i+1) landed
    writeQ();
    __syncthreads();
    COMPUTE_PHASED(1, (i + 3) * 64, issueQ1, issueQ2, issueQ3, issueQ4);
  }
  WAIT_VMCNT(12);                   // tile 6 (P) landed; tile 7 (Q) flying
  writeP();
  __syncthreads();
  COMPUTE_PHASED(0, -1, issueP1, issueP2, issueP3, issueP4);
  WAIT_VMCNT(0);                    // tile 7 (Q) landed
  writeQ();
  __syncthreads();
  COMPUTE_PHASED(1, -1, issueQ1, issueQ2, issueQ3, issueQ4);
#undef COMPUTE_PHASED

  if (z == 2) {
    const int mmbase = m0 + wr * 64;
    const int b_ = mmbase >> 10, sbase = mmbase & 1023;
#pragma unroll
    for (int nf = 0; nf < 4; ++nf) {
#pragma unroll
      for (int r = 0; r < 4; ++r) {
        const int n = n0 + wc * 64 + nf * 16 + lg * 4 + r;
        const float bval = bias[n];
        const int h = n >> 6, dd = n & 63;
        u16x4 pk;
#pragma unroll
        for (int mf = 0; mf < 4; ++mf) {
          float vv = acc[mf][nf][r] + bval;
          vv = vv > 0.f ? vv : 0.f;
          pk[mf] = f2bf(vv);
        }
        *(u16x4*)&out[((size_t)((b_ * kH + h) * kDH + dd)) * kS + sbase + l16 * 4] = pk;
      }
    }
  } else {
#pragma unroll
    for (int mf = 0; mf < 4; ++mf) {
      const int mm = m0 + wr * 64 + mf * 16 + l16;
      const int b_ = mm >> 10, s = mm & 1023;
#pragma unroll
      for (int nf = 0; nf < 4; ++nf) {
        const int nbase = n0 + wc * 64 + nf * 16 + lg * 4;
        const int h = nbase >> 6, dd = nbase & 63;
        u16x4 pk;
#pragma unroll
        for (int r = 0; r < 4; ++r) {
          float vv = acc[mf][nf][r] + bias[nbase + r];
          vv = vv > 0.f ? vv : 0.f;
          pk[r] = f2bf(vv);
        }
        *(u16x4*)&out[((size_t)(b_ * kH + h) * kS + s) * kDH + dd] = pk;
      }
    }
  }
}

// ---------------------------------------------------------------------------
// Kernel 2: flash attention (R16 verbatim: T5 setprio, bf16 y output).
// 512 blocks (bh x 8 q-tiles of 128 rows), 4 waves x 32 q-rows; 2-deep
// pinned prefetch, counted vmcnt(5); LDS dbuf, one barrier/step.
// ---------------------------------------------------------------------------
__global__ __launch_bounds__(256)
void attn_kernel(const unsigned short* __restrict__ ws,
                 const int* __restrict__ key_mask,
                 unsigned short* __restrict__ ybf)
{
  __shared__ __align__(16) unsigned short Ks[2][64][72];
  __shared__ __align__(16) unsigned short Vts[2][64][72];
  __shared__ __align__(16) unsigned short Ps[4][32][72];
  __shared__ float kmadd[2][64];

  const unsigned short* Qw = ws;
  const unsigned short* Kw = ws + (size_t)1 * kB * kS * kD;
  const unsigned short* Vw = ws + (size_t)2 * kB * kS * kD;

  const int bid = blockIdx.x;
  const int xcd = bid & 7;
  const int j = bid >> 3;
  const int qx = j & 7;
  const int bh = (j >> 3) * 8 + xcd;

  const int q0 = qx * 128;
  const int t = threadIdx.x;
  const int w = t >> 6, lane = t & 63;
  const int l16 = lane & 15, lg = lane >> 4;
  const int b_ = bh / kH, h = bh % kH;

  const unsigned short* Qb = Qw + ((size_t)bh * kS + q0) * kDH;
  const unsigned short* Kb = Kw + (size_t)bh * kS * kDH;
  const unsigned short* Vb = Vw + (size_t)bh * kDH * kS;
  const int* km = key_mask + (bh % kB) * kS;

  const int srow = t >> 3, sc8 = (t & 7) * 8;
  const unsigned short* KbR0 = Kb + (size_t)srow * kDH + sc8;
  const unsigned short* KbR1 = Kb + (size_t)(srow + 32) * kDH + sc8;
  const unsigned short* VbR0 = Vb + (size_t)srow * kS + sc8;
  const unsigned short* VbR1 = Vb + (size_t)(srow + 32) * kS + sc8;

  bf16x8 aq[2][2];
#pragma unroll
  for (int u = 0; u < 2; ++u)
#pragma unroll
    for (int kk = 0; kk < 2; ++kk)
      aq[u][kk] = *(const bf16x8*)(Qb + (size_t)(w * 32 + u * 16 + l16) * kDH + kk * 32 + lg * 8);

  bf16x8 vone;
#pragma unroll
  for (int jj = 0; jj < 8; ++jj) vone[jj] = (short)0x3F80;

  f32x4 o[2][4] = {};
  f32x4 lacc[2] = {};

  uint4 ka0, ka1, va0, va1; int kma;
  uint4 kb0, kb1, vb0, vb1; int kmb;

  auto issueA = [&](int kv0) {
    ka0 = gload16(KbR0 + (size_t)kv0 * kDH);
    ka1 = gload16(KbR1 + (size_t)kv0 * kDH);
    va0 = gload16(VbR0 + kv0);
    va1 = gload16(VbR1 + kv0);
    kma = gload4(km + kv0 + (t & 63));
  };
  auto issueB = [&](int kv0) {
    kb0 = gload16(KbR0 + (size_t)kv0 * kDH);
    kb1 = gload16(KbR1 + (size_t)kv0 * kDH);
    vb0 = gload16(VbR0 + kv0);
    vb1 = gload16(VbR1 + kv0);
    kmb = gload4(km + kv0 + (t & 63));
  };
  auto writeA = [&]() {
    *(uint4*)&Ks[0][srow][sc8]       = ka0;
    *(uint4*)&Ks[0][srow + 32][sc8]  = ka1;
    *(uint4*)&Vts[0][srow][sc8]      = va0;
    *(uint4*)&Vts[0][srow + 32][sc8] = va1;
    if (t < 64) kmadd[0][t] = kma ? 0.f : kNeg;
  };
  auto writeB = [&]() {
    *(uint4*)&Ks[1][srow][sc8]       = kb0;
    *(uint4*)&Ks[1][srow + 32][sc8]  = kb1;
    *(uint4*)&Vts[1][srow][sc8]      = vb0;
    *(uint4*)&Vts[1][srow + 32][sc8] = vb1;
    if (t < 64) kmadd[1][t] = kmb ? 0.f : kNeg;
  };
  auto compute = [&](int buf) {
    f32x4 sc[2][4] = {};
    __builtin_amdgcn_s_setprio(1);
#pragma unroll
    for (int kk = 0; kk < 2; ++kk) {
#pragma unroll
      for (int nf = 0; nf < 4; ++nf) {
        bf16x8 bfr = *(const bf16x8*)&Ks[buf][nf * 16 + l16][kk * 32 + lg * 8];
#pragma unroll
        for (int u = 0; u < 2; ++u)
          sc[u][nf] = __builtin_amdgcn_mfma_f32_16x16x32_bf16(aq[u][kk], bfr, sc[u][nf], 0, 0, 0);
      }
    }
    __builtin_amdgcn_s_setprio(0);
    float madd[4];
#pragma unroll
    for (int nf = 0; nf < 4; ++nf) madd[nf] = kmadd[buf][nf * 16 + l16];
#pragma unroll
    for (int u = 0; u < 2; ++u) {
#pragma unroll
      for (int r = 0; r < 4; ++r) {
        const float p0 = EXP2F(fmaf(sc[u][0][r], kScaleLog2e, madd[0]));
        const float p1 = EXP2F(fmaf(sc[u][1][r], kScaleLog2e, madd[1]));
        const float p2 = EXP2F(fmaf(sc[u][2][r], kScaleLog2e, madd[2]));
        const float p3 = EXP2F(fmaf(sc[u][3][r], kScaleLog2e, madd[3]));
        const int prow = u * 16 + lg * 4 + r;
        uint2 pw;
        pw.x = __builtin_amdgcn_perm(__float_as_uint(p1), __float_as_uint(p0), 0x07060302u);
        pw.y = __builtin_amdgcn_perm(__float_as_uint(p3), __float_as_uint(p2), 0x07060302u);
        *(uint2*)&Ps[w][prow][l16 * 4] = pw;
      }
    }
    __builtin_amdgcn_s_setprio(1);
#pragma unroll
    for (int kk = 0; kk < 2; ++kk) {
      bf16x8 a0 = *(const bf16x8*)&Ps[w][l16][kk * 32 + lg * 8];
      bf16x8 a1 = *(const bf16x8*)&Ps[w][16 + l16][kk * 32 + lg * 8];
#pragma unroll
      for (int nd = 0; nd < 4; ++nd) {
        bf16x8 bfr = *(const bf16x8*)&Vts[buf][nd * 16 + l16][kk * 32 + lg * 8];
        o[0][nd] = __builtin_amdgcn_mfma_f32_16x16x32_bf16(a0, bfr, o[0][nd], 0, 0, 0);
        o[1][nd] = __builtin_amdgcn_mfma_f32_16x16x32_bf16(a1, bfr, o[1][nd], 0, 0, 0);
      }
      lacc[0] = __builtin_amdgcn_mfma_f32_16x16x32_bf16(a0, vone, lacc[0], 0, 0, 0);
      lacc[1] = __builtin_amdgcn_mfma_f32_16x16x32_bf16(a1, vone, lacc[1], 0, 0, 0);
    }
    __builtin_amdgcn_s_setprio(0);
  };

  issueA(0);
  issueB(64);
  for (int i = 0; i < 14; i += 2) {
    WAIT_VMCNT(5);
    writeA();
    issueA((i + 2) * 64);
    __syncthreads();
    compute(0);
    WAIT_VMCNT(5);
    writeB();
    issueB((i + 3) * 64);
    __syncthreads();
    compute(1);
  }
  WAIT_VMCNT(5);
  writeA();
  __syncthreads();
  compute(0);
  WAIT_VMCNT(0);
  writeB();
  __syncthreads();
  compute(1);

#pragma unroll
  for (int u = 0; u < 2; ++u) {
    float rinv[4];
#pragma unroll
    for (int r = 0; r < 4; ++r) rinv[r] = 1.f / lacc[u][r];
#pragma unroll
    for (int nd = 0; nd < 4; ++nd) {
#pragma unroll
      for (int r = 0; r < 4; ++r) {
        const int srowq = q0 + w * 32 + u * 16 + lg * 4 + r;
        ybf[((size_t)b_ * kS + srowq) * kD + h * kDH + nd * 16 + l16] =
            f2bf(o[u][nd][r] * rinv[r]);
      }
    }
  }
}

// ---------------------------------------------------------------------------
// Kernel 3: out = LN(qmask*y + q) * gamma + beta. y read as bf16 from ws.
// ---------------------------------------------------------------------------
__global__ __launch_bounds__(256)
void ln_kernel(const unsigned short* __restrict__ ybf, const float* __restrict__ q,
               const int* __restrict__ qmask,
               const float* __restrict__ gamma, const float* __restrict__ beta,
               float* __restrict__ out)
{
  const int w = threadIdx.x >> 6, lane = threadIdx.x & 63;
  const int row = blockIdx.x * 4 + w;            // 0..8191
  const int b_ = row >> 10, s = row & 1023;
  const int d0 = lane * 8;
  const int h = d0 >> 6;

  const unsigned short* yp = ybf + (size_t)row * kD + d0;
  const float* qp = q + (size_t)row * kD + d0;
  const int qm = qmask[((b_ * kH + h) % kB) * kS + s];

  u16x8 yv = *(const u16x8*)yp;
  float4 q0 = *(const float4*)qp, q1 = *(const float4*)(qp + 4);
  float vals[8];
#pragma unroll
  for (int jj = 0; jj < 8; ++jj) vals[jj] = bf2f(yv[jj]);
  float qs[8]   = { q0.x, q0.y, q0.z, q0.w, q1.x, q1.y, q1.z, q1.w };

  float sum = 0.f, ss = 0.f;
#pragma unroll
  for (int jj = 0; jj < 8; ++jj) {
    const float val = (qm ? vals[jj] : 0.f) + qs[jj];
    vals[jj] = val; sum += val; ss += val * val;
  }
#pragma unroll
  for (int off = 1; off < 64; off <<= 1) {
    sum += __shfl_xor(sum, off);
    ss  += __shfl_xor(ss, off);
  }
  const float mu = sum * (1.f / kD);
  const float var = ss * (1.f / kD) - mu * mu;
  const float rstd = rsqrtf(var + 1e-6f);

  float4 g0 = *(const float4*)(gamma + d0), g1 = *(const float4*)(gamma + d0 + 4);
  float4 be0 = *(const float4*)(beta + d0), be1 = *(const float4*)(beta + d0 + 4);
  float gs[8] = { g0.x, g0.y, g0.z, g0.w, g1.x, g1.y, g1.z, g1.w };
  float bs[8] = { be0.x, be0.y, be0.z, be0.w, be1.x, be1.y, be1.z, be1.w };

  float4 o0, o1;
  o0.x = gs[0] * (vals[0] - mu) * rstd + bs[0];
  o0.y = gs[1] * (vals[1] - mu) * rstd + bs[1];
  o0.z = gs[2] * (vals[2] - mu) * rstd + bs[2];
  o0.w = gs[3] * (vals[3] - mu) * rstd + bs[3];
  o1.x = gs[4] * (vals[4] - mu) * rstd + bs[4];
  o1.y = gs[5] * (vals[5] - mu) * rstd + bs[5];
  o1.z = gs[6] * (vals[6] - mu) * rstd + bs[6];
  o1.w = gs[7] * (vals[7] - mu) * rstd + bs[7];
  *(float4*)(out + (size_t)row * kD + d0) = o0;
  *(float4*)(out + (size_t)row * kD + d0 + 4) = o1;
}

extern "C" void kernel_launch(void* const* d_in, const int* in_sizes, int n_in,
                              void* d_out, int out_size, void* d_ws, size_t ws_size,
                              hipStream_t stream) {
  const float* q  = (const float*)d_in[0];
  const float* k  = (const float*)d_in[1];
  const float* v  = (const float*)d_in[2];
  const int* qmask = (const int*)d_in[3];
  const int* kmask = (const int*)d_in[4];
  const float* Wq = (const float*)d_in[5];
  const float* bq = (const float*)d_in[6];
  const float* Wk = (const float*)d_in[7];
  const float* bk = (const float*)d_in[8];
  const float* Wv = (const float*)d_in[9];
  const float* bv = (const float*)d_in[10];
  const float* gamma = (const float*)d_in[11];
  const float* beta  = (const float*)d_in[12];
  float* out = (float*)d_out;
  unsigned short* wsqkv = (unsigned short*)d_ws;        // 0..24MB: Q,K,V^T bf16
  unsigned short* ybf   = wsqkv + (size_t)3 * 4194304;  // 24..32.4MB: y bf16
  unsigned short* wbf   = (unsigned short*)d_out;       // d_out scratch for W bf16

  wcvt_kernel<<<768, 256, 0, stream>>>(Wq, Wk, Wv, wbf);
  qkv_gemm_kernel<<<768, 256, 0, stream>>>(
      q, k, v, wbf, bq, bk, bv, wsqkv);
  attn_kernel<<<512, 256, 0, stream>>>(wsqkv, kmask, ybf);
  ln_kernel<<<2048, 256, 0, stream>>>(ybf, q, qmask, gamma, beta, out);
}

// Round 18
// 68.533 us; speedup vs baseline: 1.2009x; 1.0062x over previous
//
#include <hip/hip_runtime.h>
#include <hip/hip_bf16.h>
#include <stdint.h>

constexpr int kB = 8, kH = 8, kS = 1024, kD = 512, kDH = 64;
constexpr float kNeg = -1e9f;
constexpr float kScaleLog2e = 0.125f * 1.4426950408889634f;

typedef __attribute__((ext_vector_type(8))) short bf16x8;
typedef __attribute__((ext_vector_type(8))) unsigned short u16x8;
typedef __attribute__((ext_vector_type(4))) float f32x4;
typedef __attribute__((ext_vector_type(4))) unsigned short u16x4;

__device__ __forceinline__ unsigned short f2bf(float f) {
  union { float f; unsigned int u; } a; a.f = f;
  return (unsigned short)((a.u + 0x7FFFu + ((a.u >> 16) & 1u)) >> 16);
}
__device__ __forceinline__ float bf2f(unsigned short u) {
  union { unsigned int u; float f; } a; a.u = ((unsigned int)u) << 16;
  return a.f;
}
__device__ __forceinline__ unsigned int pk2bf(float lo, float hi) {
  union { __hip_bfloat162 h; unsigned int u; } cv;
  cv.h = __float22bfloat162_rn(make_float2(lo, hi));
  return cv.u;
}
// Pinned global loads (inline asm: cannot be sunk/CSE'd/re-materialized).
__device__ __forceinline__ uint4 gload16(const void* p) {
  uint4 r;
  asm volatile("global_load_dwordx4 %0, %1, off" : "=v"(r) : "v"(p));
  return r;
}
__device__ __forceinline__ int gload4(const void* p) {
  int r;
  asm volatile("global_load_dword %0, %1, off" : "=v"(r) : "v"(p));
  return r;
}
#define WAIT_VMCNT(N) do { \
  asm volatile("s_waitcnt vmcnt(" #N ")" ::: "memory"); \
  __builtin_amdgcn_sched_barrier(0); } while (0)

__device__ __forceinline__ uint4 cvt4(uint4 a, uint4 b) {
  uint4 r;
  r.x = pk2bf(__uint_as_float(a.x), __uint_as_float(a.y));
  r.y = pk2bf(__uint_as_float(a.z), __uint_as_float(a.w));
  r.z = pk2bf(__uint_as_float(b.x), __uint_as_float(b.y));
  r.w = pk2bf(__uint_as_float(b.z), __uint_as_float(b.w));
  return r;
}

#if __has_builtin(__builtin_amdgcn_exp2f)
#define EXP2F(x) __builtin_amdgcn_exp2f(x)
#else
#define EXP2F(x) exp2f(x)
#endif

// ---------------------------------------------------------------------------
// Kernel 1: C = relu(X @ W^T + bias). R17's phase-split schedule, with W's
// f32->bf16 conversion FUSED into B staging (wcvt kernel removed: -1 launch,
// -1.3us, no d_out scratch). Both A (X) and B (W) load f32 + cvt4 at the LDS
// write. 2-deep pinned prefetch, counted vmcnt(16) (16 loads/set now).
// 4 phases per K-step: {ds_read frags; issue 4 of 16 next-tile loads;
// setprio(1); 8 MFMA; setprio(0); barrier}.
//   Q,K: [b*H+h][s][64]; V: [b*H+h][d][s] with s k-permuted per 64-block.
// ---------------------------------------------------------------------------
__global__ __launch_bounds__(256)
void qkv_gemm_kernel(const float* __restrict__ xq, const float* __restrict__ xk,
                     const float* __restrict__ xv,
                     const float* __restrict__ wq, const float* __restrict__ wk,
                     const float* __restrict__ wv,
                     const float* __restrict__ bq, const float* __restrict__ bk,
                     const float* __restrict__ bv,
                     unsigned short* __restrict__ wsout)
{
  __shared__ __align__(16) unsigned short As[2][128][72];
  __shared__ __align__(16) unsigned short Bs[2][128][72];

  const int bid = blockIdx.x;
  const int xcd = bid & 7;
  const int j = bid >> 3;
  const int x = j & 3;
  const int g = (j >> 2) * 8 + xcd;        // 0..191
  const int z = g >> 6;                    // 0..2
  const int y = g & 63;                    // 0..63

  const float* X    = (z == 0) ? xq : (z == 1) ? xk : xv;
  const float* W    = (z == 0) ? wq : (z == 1) ? wk : wv;
  const float* bias = (z == 0) ? bq : (z == 1) ? bk : bv;
  unsigned short* out = wsout + (size_t)z * (kB * kS * kD);

  const int m0 = y * 128;
  const int n0 = x * 128;
  const int t = threadIdx.x;
  const int lane = t & 63;
  const int w = t >> 6;
  const int wr = w >> 1, wc = w & 1;
  const int l16 = lane & 15, lg = lane >> 4;

  const int row = t >> 3, c8 = (t & 7) * 8;
  const float* Xr = X + (size_t)(m0 + row) * kD + c8;
  const float* Wr = W + (size_t)(n0 + row) * kD + c8;

  f32x4 acc[4][4] = {};
  uint4 pa0, pa1, pa2, pa3, pa4, pa5, pa6, pa7;
  uint4 pb0l, pb0h, pb1l, pb1h, pb2l, pb2h, pb3l, pb3h;
  uint4 qa0, qa1, qa2, qa3, qa4, qa5, qa6, qa7;
  uint4 qb0l, qb0h, qb1l, qb1h, qb2l, qb2h, qb3l, qb3h;

  // full issues (prologue): 16 loads/set
  auto issueP = [&](int kt) {
    pa0 = gload16(Xr + kt);            pa1 = gload16(Xr + kt + 4);
    pa2 = gload16(Xr + 32 * kD + kt);  pa3 = gload16(Xr + 32 * kD + kt + 4);
    pa4 = gload16(Xr + 64 * kD + kt);  pa5 = gload16(Xr + 64 * kD + kt + 4);
    pa6 = gload16(Xr + 96 * kD + kt);  pa7 = gload16(Xr + 96 * kD + kt + 4);
    pb0l = gload16(Wr + kt);            pb0h = gload16(Wr + kt + 4);
    pb1l = gload16(Wr + 32 * kD + kt);  pb1h = gload16(Wr + 32 * kD + kt + 4);
    pb2l = gload16(Wr + 64 * kD + kt);  pb2h = gload16(Wr + 64 * kD + kt + 4);
    pb3l = gload16(Wr + 96 * kD + kt);  pb3h = gload16(Wr + 96 * kD + kt + 4);
  };
  auto issueQ = [&](int kt) {
    qa0 = gload16(Xr + kt);            qa1 = gload16(Xr + kt + 4);
    qa2 = gload16(Xr + 32 * kD + kt);  qa3 = gload16(Xr + 32 * kD + kt + 4);
    qa4 = gload16(Xr + 64 * kD + kt);  qa5 = gload16(Xr + 64 * kD + kt + 4);
    qa6 = gload16(Xr + 96 * kD + kt);  qa7 = gload16(Xr + 96 * kD + kt + 4);
    qb0l = gload16(Wr + kt);            qb0h = gload16(Wr + kt + 4);
    qb1l = gload16(Wr + 32 * kD + kt);  qb1h = gload16(Wr + 32 * kD + kt + 4);
    qb2l = gload16(Wr + 64 * kD + kt);  qb2h = gload16(Wr + 64 * kD + kt + 4);
    qb3l = gload16(Wr + 96 * kD + kt);  qb3h = gload16(Wr + 96 * kD + kt + 4);
  };
  // quarter issues (4 loads each, interleaved into the 4 compute phases)
  auto issueP1 = [&](int kt) {
    pa0 = gload16(Xr + kt);            pa1 = gload16(Xr + kt + 4);
    pa2 = gload16(Xr + 32 * kD + kt);  pa3 = gload16(Xr + 32 * kD + kt + 4);
  };
  auto issueP2 = [&](int kt) {
    pa4 = gload16(Xr + 64 * kD + kt);  pa5 = gload16(Xr + 64 * kD + kt + 4);
    pa6 = gload16(Xr + 96 * kD + kt);  pa7 = gload16(Xr + 96 * kD + kt + 4);
  };
  auto issueP3 = [&](int kt) {
    pb0l = gload16(Wr + kt);            pb0h = gload16(Wr + kt + 4);
    pb1l = gload16(Wr + 32 * kD + kt);  pb1h = gload16(Wr + 32 * kD + kt + 4);
  };
  auto issueP4 = [&](int kt) {
    pb2l = gload16(Wr + 64 * kD + kt);  pb2h = gload16(Wr + 64 * kD + kt + 4);
    pb3l = gload16(Wr + 96 * kD + kt);  pb3h = gload16(Wr + 96 * kD + kt + 4);
  };
  auto issueQ1 = [&](int kt) {
    qa0 = gload16(Xr + kt);            qa1 = gload16(Xr + kt + 4);
    qa2 = gload16(Xr + 32 * kD + kt);  qa3 = gload16(Xr + 32 * kD + kt + 4);
  };
  auto issueQ2 = [&](int kt) {
    qa4 = gload16(Xr + 64 * kD + kt);  qa5 = gload16(Xr + 64 * kD + kt + 4);
    qa6 = gload16(Xr + 96 * kD + kt);  qa7 = gload16(Xr + 96 * kD + kt + 4);
  };
  auto issueQ3 = [&](int kt) {
    qb0l = gload16(Wr + kt);            qb0h = gload16(Wr + kt + 4);
    qb1l = gload16(Wr + 32 * kD + kt);  qb1h = gload16(Wr + 32 * kD + kt + 4);
  };
  auto issueQ4 = [&](int kt) {
    qb2l = gload16(Wr + 64 * kD + kt);  qb2h = gload16(Wr + 64 * kD + kt + 4);
    qb3l = gload16(Wr + 96 * kD + kt);  qb3h = gload16(Wr + 96 * kD + kt + 4);
  };
  auto writeP = [&]() {
    *(uint4*)&As[0][row][c8]      = cvt4(pa0, pa1);
    *(uint4*)&As[0][row + 32][c8] = cvt4(pa2, pa3);
    *(uint4*)&As[0][row + 64][c8] = cvt4(pa4, pa5);
    *(uint4*)&As[0][row + 96][c8] = cvt4(pa6, pa7);
    *(uint4*)&Bs[0][row][c8]      = cvt4(pb0l, pb0h);
    *(uint4*)&Bs[0][row + 32][c8] = cvt4(pb1l, pb1h);
    *(uint4*)&Bs[0][row + 64][c8] = cvt4(pb2l, pb2h);
    *(uint4*)&Bs[0][row + 96][c8] = cvt4(pb3l, pb3h);
  };
  auto writeQ = [&]() {
    *(uint4*)&As[1][row][c8]      = cvt4(qa0, qa1);
    *(uint4*)&As[1][row + 32][c8] = cvt4(qa2, qa3);
    *(uint4*)&As[1][row + 64][c8] = cvt4(qa4, qa5);
    *(uint4*)&As[1][row + 96][c8] = cvt4(qa6, qa7);
    *(uint4*)&Bs[1][row][c8]      = cvt4(qb0l, qb0h);
    *(uint4*)&Bs[1][row + 32][c8] = cvt4(qb1l, qb1h);
    *(uint4*)&Bs[1][row + 64][c8] = cvt4(qb2l, qb2h);
    *(uint4*)&Bs[1][row + 96][c8] = cvt4(qb3l, qb3h);
  };

#define COMPUTE_PHASED(BUF, KT, I1, I2, I3, I4)                               \
  do {                                                                        \
    bf16x8 av0, av1, av2, av3, bv0, bv1;                                      \
    /* phase 1: kk=0, nf=0,1 */                                               \
    av0 = *(const bf16x8*)&As[BUF][wr * 64 +  0 + l16][lg * 8];               \
    av1 = *(const bf16x8*)&As[BUF][wr * 64 + 16 + l16][lg * 8];               \
    av2 = *(const bf16x8*)&As[BUF][wr * 64 + 32 + l16][lg * 8];               \
    av3 = *(const bf16x8*)&As[BUF][wr * 64 + 48 + l16][lg * 8];               \
    bv0 = *(const bf16x8*)&Bs[BUF][wc * 64 +  0 + l16][lg * 8];               \
    bv1 = *(const bf16x8*)&Bs[BUF][wc * 64 + 16 + l16][lg * 8];               \
    if (KT >= 0) I1(KT);                                                      \
    __builtin_amdgcn_s_setprio(1);                                            \
    acc[0][0] = __builtin_amdgcn_mfma_f32_16x16x32_bf16(bv0, av0, acc[0][0], 0, 0, 0); \
    acc[1][0] = __builtin_amdgcn_mfma_f32_16x16x32_bf16(bv0, av1, acc[1][0], 0, 0, 0); \
    acc[2][0] = __builtin_amdgcn_mfma_f32_16x16x32_bf16(bv0, av2, acc[2][0], 0, 0, 0); \
    acc[3][0] = __builtin_amdgcn_mfma_f32_16x16x32_bf16(bv0, av3, acc[3][0], 0, 0, 0); \
    acc[0][1] = __builtin_amdgcn_mfma_f32_16x16x32_bf16(bv1, av0, acc[0][1], 0, 0, 0); \
    acc[1][1] = __builtin_amdgcn_mfma_f32_16x16x32_bf16(bv1, av1, acc[1][1], 0, 0, 0); \
    acc[2][1] = __builtin_amdgcn_mfma_f32_16x16x32_bf16(bv1, av2, acc[2][1], 0, 0, 0); \
    acc[3][1] = __builtin_amdgcn_mfma_f32_16x16x32_bf16(bv1, av3, acc[3][1], 0, 0, 0); \
    __builtin_amdgcn_s_setprio(0);                                            \
    __syncthreads();                                                          \
    /* phase 2: kk=0, nf=2,3 */                                               \
    bv0 = *(const bf16x8*)&Bs[BUF][wc * 64 + 32 + l16][lg * 8];               \
    bv1 = *(const bf16x8*)&Bs[BUF][wc * 64 + 48 + l16][lg * 8];               \
    if (KT >= 0) I2(KT);                                                      \
    __builtin_amdgcn_s_setprio(1);                                            \
    acc[0][2] = __builtin_amdgcn_mfma_f32_16x16x32_bf16(bv0, av0, acc[0][2], 0, 0, 0); \
    acc[1][2] = __builtin_amdgcn_mfma_f32_16x16x32_bf16(bv0, av1, acc[1][2], 0, 0, 0); \
    acc[2][2] = __builtin_amdgcn_mfma_f32_16x16x32_bf16(bv0, av2, acc[2][2], 0, 0, 0); \
    acc[3][2] = __builtin_amdgcn_mfma_f32_16x16x32_bf16(bv0, av3, acc[3][2], 0, 0, 0); \
    acc[0][3] = __builtin_amdgcn_mfma_f32_16x16x32_bf16(bv1, av0, acc[0][3], 0, 0, 0); \
    acc[1][3] = __builtin_amdgcn_mfma_f32_16x16x32_bf16(bv1, av1, acc[1][3], 0, 0, 0); \
    acc[2][3] = __builtin_amdgcn_mfma_f32_16x16x32_bf16(bv1, av2, acc[2][3], 0, 0, 0); \
    acc[3][3] = __builtin_amdgcn_mfma_f32_16x16x32_bf16(bv1, av3, acc[3][3], 0, 0, 0); \
    __builtin_amdgcn_s_setprio(0);                                            \
    __syncthreads();                                                          \
    /* phase 3: kk=1, nf=0,1 */                                               \
    av0 = *(const bf16x8*)&As[BUF][wr * 64 +  0 + l16][32 + lg * 8];          \
    av1 = *(const bf16x8*)&As[BUF][wr * 64 + 16 + l16][32 + lg * 8];          \
    av2 = *(const bf16x8*)&As[BUF][wr * 64 + 32 + l16][32 + lg * 8];          \
    av3 = *(const bf16x8*)&As[BUF][wr * 64 + 48 + l16][32 + lg * 8];          \
    bv0 = *(const bf16x8*)&Bs[BUF][wc * 64 +  0 + l16][32 + lg * 8];          \
    bv1 = *(const bf16x8*)&Bs[BUF][wc * 64 + 16 + l16][32 + lg * 8];          \
    if (KT >= 0) I3(KT);                                                      \
    __builtin_amdgcn_s_setprio(1);                                            \
    acc[0][0] = __builtin_amdgcn_mfma_f32_16x16x32_bf16(bv0, av0, acc[0][0], 0, 0, 0); \
    acc[1][0] = __builtin_amdgcn_mfma_f32_16x16x32_bf16(bv0, av1, acc[1][0], 0, 0, 0); \
    acc[2][0] = __builtin_amdgcn_mfma_f32_16x16x32_bf16(bv0, av2, acc[2][0], 0, 0, 0); \
    acc[3][0] = __builtin_amdgcn_mfma_f32_16x16x32_bf16(bv0, av3, acc[3][0], 0, 0, 0); \
    acc[0][1] = __builtin_amdgcn_mfma_f32_16x16x32_bf16(bv1, av0, acc[0][1], 0, 0, 0); \
    acc[1][1] = __builtin_amdgcn_mfma_f32_16x16x32_bf16(bv1, av1, acc[1][1], 0, 0, 0); \
    acc[2][1] = __builtin_amdgcn_mfma_f32_16x16x32_bf16(bv1, av2, acc[2][1], 0, 0, 0); \
    acc[3][1] = __builtin_amdgcn_mfma_f32_16x16x32_bf16(bv1, av3, acc[3][1], 0, 0, 0); \
    __builtin_amdgcn_s_setprio(0);                                            \
    __syncthreads();                                                          \
    /* phase 4: kk=1, nf=2,3 */                                               \
    bv0 = *(const bf16x8*)&Bs[BUF][wc * 64 + 32 + l16][32 + lg * 8];          \
    bv1 = *(const bf16x8*)&Bs[BUF][wc * 64 + 48 + l16][32 + lg * 8];          \
    if (KT >= 0) I4(KT);                                                      \
    __builtin_amdgcn_s_setprio(1);                                            \
    acc[0][2] = __builtin_amdgcn_mfma_f32_16x16x32_bf16(bv0, av0, acc[0][2], 0, 0, 0); \
    acc[1][2] = __builtin_amdgcn_mfma_f32_16x16x32_bf16(bv0, av1, acc[1][2], 0, 0, 0); \
    acc[2][2] = __builtin_amdgcn_mfma_f32_16x16x32_bf16(bv0, av2, acc[2][2], 0, 0, 0); \
    acc[3][2] = __builtin_amdgcn_mfma_f32_16x16x32_bf16(bv0, av3, acc[3][2], 0, 0, 0); \
    acc[0][3] = __builtin_amdgcn_mfma_f32_16x16x32_bf16(bv1, av0, acc[0][3], 0, 0, 0); \
    acc[1][3] = __builtin_amdgcn_mfma_f32_16x16x32_bf16(bv1, av1, acc[1][3], 0, 0, 0); \
    acc[2][3] = __builtin_amdgcn_mfma_f32_16x16x32_bf16(bv1, av2, acc[2][3], 0, 0, 0); \
    acc[3][3] = __builtin_amdgcn_mfma_f32_16x16x32_bf16(bv1, av3, acc[3][3], 0, 0, 0); \
    __builtin_amdgcn_s_setprio(0);                                            \
  } while (0)

  issueP(0);
  issueQ(64);
#pragma unroll
  for (int i = 0; i < 6; i += 2) {
    WAIT_VMCNT(16);                 // set P (tile i) landed; Q still flying
    writeP();
    __syncthreads();
    COMPUTE_PHASED(0, (i + 2) * 64, issueP1, issueP2, issueP3, issueP4);
    WAIT_VMCNT(16);                 // set Q (tile i+1) landed
    writeQ();
    __syncthreads();
    COMPUTE_PHASED(1, (i + 3) * 64, issueQ1, issueQ2, issueQ3, issueQ4);
  }
  WAIT_VMCNT(16);                   // tile 6 (P) landed; tile 7 (Q) flying
  writeP();
  __syncthreads();
  COMPUTE_PHASED(0, -1, issueP1, issueP2, issueP3, issueP4);
  WAIT_VMCNT(0);                    // tile 7 (Q) landed
  writeQ();
  __syncthreads();
  COMPUTE_PHASED(1, -1, issueQ1, issueQ2, issueQ3, issueQ4);
#undef COMPUTE_PHASED

  if (z == 2) {
    const int mmbase = m0 + wr * 64;
    const int b_ = mmbase >> 10, sbase = mmbase & 1023;
#pragma unroll
    for (int nf = 0; nf < 4; ++nf) {
#pragma unroll
      for (int r = 0; r < 4; ++r) {
        const int n = n0 + wc * 64 + nf * 16 + lg * 4 + r;
        const float bval = bias[n];
        const int h = n >> 6, dd = n & 63;
        u16x4 pk;
#pragma unroll
        for (int mf = 0; mf < 4; ++mf) {
          float vv = acc[mf][nf][r] + bval;
          vv = vv > 0.f ? vv : 0.f;
          pk[mf] = f2bf(vv);
        }
        *(u16x4*)&out[((size_t)((b_ * kH + h) * kDH + dd)) * kS + sbase + l16 * 4] = pk;
      }
    }
  } else {
#pragma unroll
    for (int mf = 0; mf < 4; ++mf) {
      const int mm = m0 + wr * 64 + mf * 16 + l16;
      const int b_ = mm >> 10, s = mm & 1023;
#pragma unroll
      for (int nf = 0; nf < 4; ++nf) {
        const int nbase = n0 + wc * 64 + nf * 16 + lg * 4;
        const int h = nbase >> 6, dd = nbase & 63;
        u16x4 pk;
#pragma unroll
        for (int r = 0; r < 4; ++r) {
          float vv = acc[mf][nf][r] + bias[nbase + r];
          vv = vv > 0.f ? vv : 0.f;
          pk[r] = f2bf(vv);
        }
        *(u16x4*)&out[((size_t)(b_ * kH + h) * kS + s) * kDH + dd] = pk;
      }
    }
  }
}

// ---------------------------------------------------------------------------
// Kernel 2: flash attention (R16 verbatim: T5 setprio, bf16 y output).
// 512 blocks (bh x 8 q-tiles of 128 rows), 4 waves x 32 q-rows; 2-deep
// pinned prefetch, counted vmcnt(5); LDS dbuf, one barrier/step.
// ---------------------------------------------------------------------------
__global__ __launch_bounds__(256)
void attn_kernel(const unsigned short* __restrict__ ws,
                 const int* __restrict__ key_mask,
                 unsigned short* __restrict__ ybf)
{
  __shared__ __align__(16) unsigned short Ks[2][64][72];
  __shared__ __align__(16) unsigned short Vts[2][64][72];
  __shared__ __align__(16) unsigned short Ps[4][32][72];
  __shared__ float kmadd[2][64];

  const unsigned short* Qw = ws;
  const unsigned short* Kw = ws + (size_t)1 * kB * kS * kD;
  const unsigned short* Vw = ws + (size_t)2 * kB * kS * kD;

  const int bid = blockIdx.x;
  const int xcd = bid & 7;
  const int j = bid >> 3;
  const int qx = j & 7;
  const int bh = (j >> 3) * 8 + xcd;

  const int q0 = qx * 128;
  const int t = threadIdx.x;
  const int w = t >> 6, lane = t & 63;
  const int l16 = lane & 15, lg = lane >> 4;
  const int b_ = bh / kH, h = bh % kH;

  const unsigned short* Qb = Qw + ((size_t)bh * kS + q0) * kDH;
  const unsigned short* Kb = Kw + (size_t)bh * kS * kDH;
  const unsigned short* Vb = Vw + (size_t)bh * kDH * kS;
  const int* km = key_mask + (bh % kB) * kS;

  const int srow = t >> 3, sc8 = (t & 7) * 8;
  const unsigned short* KbR0 = Kb + (size_t)srow * kDH + sc8;
  const unsigned short* KbR1 = Kb + (size_t)(srow + 32) * kDH + sc8;
  const unsigned short* VbR0 = Vb + (size_t)srow * kS + sc8;
  const unsigned short* VbR1 = Vb + (size_t)(srow + 32) * kS + sc8;

  bf16x8 aq[2][2];
#pragma unroll
  for (int u = 0; u < 2; ++u)
#pragma unroll
    for (int kk = 0; kk < 2; ++kk)
      aq[u][kk] = *(const bf16x8*)(Qb + (size_t)(w * 32 + u * 16 + l16) * kDH + kk * 32 + lg * 8);

  bf16x8 vone;
#pragma unroll
  for (int jj = 0; jj < 8; ++jj) vone[jj] = (short)0x3F80;

  f32x4 o[2][4] = {};
  f32x4 lacc[2] = {};

  uint4 ka0, ka1, va0, va1; int kma;
  uint4 kb0, kb1, vb0, vb1; int kmb;

  auto issueA = [&](int kv0) {
    ka0 = gload16(KbR0 + (size_t)kv0 * kDH);
    ka1 = gload16(KbR1 + (size_t)kv0 * kDH);
    va0 = gload16(VbR0 + kv0);
    va1 = gload16(VbR1 + kv0);
    kma = gload4(km + kv0 + (t & 63));
  };
  auto issueB = [&](int kv0) {
    kb0 = gload16(KbR0 + (size_t)kv0 * kDH);
    kb1 = gload16(KbR1 + (size_t)kv0 * kDH);
    vb0 = gload16(VbR0 + kv0);
    vb1 = gload16(VbR1 + kv0);
    kmb = gload4(km + kv0 + (t & 63));
  };
  auto writeA = [&]() {
    *(uint4*)&Ks[0][srow][sc8]       = ka0;
    *(uint4*)&Ks[0][srow + 32][sc8]  = ka1;
    *(uint4*)&Vts[0][srow][sc8]      = va0;
    *(uint4*)&Vts[0][srow + 32][sc8] = va1;
    if (t < 64) kmadd[0][t] = kma ? 0.f : kNeg;
  };
  auto writeB = [&]() {
    *(uint4*)&Ks[1][srow][sc8]       = kb0;
    *(uint4*)&Ks[1][srow + 32][sc8]  = kb1;
    *(uint4*)&Vts[1][srow][sc8]      = vb0;
    *(uint4*)&Vts[1][srow + 32][sc8] = vb1;
    if (t < 64) kmadd[1][t] = kmb ? 0.f : kNeg;
  };
  auto compute = [&](int buf) {
    f32x4 sc[2][4] = {};
    __builtin_amdgcn_s_setprio(1);
#pragma unroll
    for (int kk = 0; kk < 2; ++kk) {
#pragma unroll
      for (int nf = 0; nf < 4; ++nf) {
        bf16x8 bfr = *(const bf16x8*)&Ks[buf][nf * 16 + l16][kk * 32 + lg * 8];
#pragma unroll
        for (int u = 0; u < 2; ++u)
          sc[u][nf] = __builtin_amdgcn_mfma_f32_16x16x32_bf16(aq[u][kk], bfr, sc[u][nf], 0, 0, 0);
      }
    }
    __builtin_amdgcn_s_setprio(0);
    float madd[4];
#pragma unroll
    for (int nf = 0; nf < 4; ++nf) madd[nf] = kmadd[buf][nf * 16 + l16];
#pragma unroll
    for (int u = 0; u < 2; ++u) {
#pragma unroll
      for (int r = 0; r < 4; ++r) {
        const float p0 = EXP2F(fmaf(sc[u][0][r], kScaleLog2e, madd[0]));
        const float p1 = EXP2F(fmaf(sc[u][1][r], kScaleLog2e, madd[1]));
        const float p2 = EXP2F(fmaf(sc[u][2][r], kScaleLog2e, madd[2]));
        const float p3 = EXP2F(fmaf(sc[u][3][r], kScaleLog2e, madd[3]));
        const int prow = u * 16 + lg * 4 + r;
        uint2 pw;
        pw.x = __builtin_amdgcn_perm(__float_as_uint(p1), __float_as_uint(p0), 0x07060302u);
        pw.y = __builtin_amdgcn_perm(__float_as_uint(p3), __float_as_uint(p2), 0x07060302u);
        *(uint2*)&Ps[w][prow][l16 * 4] = pw;
      }
    }
    __builtin_amdgcn_s_setprio(1);
#pragma unroll
    for (int kk = 0; kk < 2; ++kk) {
      bf16x8 a0 = *(const bf16x8*)&Ps[w][l16][kk * 32 + lg * 8];
      bf16x8 a1 = *(const bf16x8*)&Ps[w][16 + l16][kk * 32 + lg * 8];
#pragma unroll
      for (int nd = 0; nd < 4; ++nd) {
        bf16x8 bfr = *(const bf16x8*)&Vts[buf][nd * 16 + l16][kk * 32 + lg * 8];
        o[0][nd] = __builtin_amdgcn_mfma_f32_16x16x32_bf16(a0, bfr, o[0][nd], 0, 0, 0);
        o[1][nd] = __builtin_amdgcn_mfma_f32_16x16x32_bf16(a1, bfr, o[1][nd], 0, 0, 0);
      }
      lacc[0] = __builtin_amdgcn_mfma_f32_16x16x32_bf16(a0, vone, lacc[0], 0, 0, 0);
      lacc[1] = __builtin_amdgcn_mfma_f32_16x16x32_bf16(a1, vone, lacc[1], 0, 0, 0);
    }
    __builtin_amdgcn_s_setprio(0);
  };

  issueA(0);
  issueB(64);
  for (int i = 0; i < 14; i += 2) {
    WAIT_VMCNT(5);
    writeA();
    issueA((i + 2) * 64);
    __syncthreads();
    compute(0);
    WAIT_VMCNT(5);
    writeB();
    issueB((i + 3) * 64);
    __syncthreads();
    compute(1);
  }
  WAIT_VMCNT(5);
  writeA();
  __syncthreads();
  compute(0);
  WAIT_VMCNT(0);
  writeB();
  __syncthreads();
  compute(1);

#pragma unroll
  for (int u = 0; u < 2; ++u) {
    float rinv[4];
#pragma unroll
    for (int r = 0; r < 4; ++r) rinv[r] = 1.f / lacc[u][r];
#pragma unroll
    for (int nd = 0; nd < 4; ++nd) {
#pragma unroll
      for (int r = 0; r < 4; ++r) {
        const int srowq = q0 + w * 32 + u * 16 + lg * 4 + r;
        ybf[((size_t)b_ * kS + srowq) * kD + h * kDH + nd * 16 + l16] =
            f2bf(o[u][nd][r] * rinv[r]);
      }
    }
  }
}

// ---------------------------------------------------------------------------
// Kernel 3: out = LN(qmask*y + q) * gamma + beta. y read as bf16 from ws.
// ---------------------------------------------------------------------------
__global__ __launch_bounds__(256)
void ln_kernel(const unsigned short* __restrict__ ybf, const float* __restrict__ q,
               const int* __restrict__ qmask,
               const float* __restrict__ gamma, const float* __restrict__ beta,
               float* __restrict__ out)
{
  const int w = threadIdx.x >> 6, lane = threadIdx.x & 63;
  const int row = blockIdx.x * 4 + w;            // 0..8191
  const int b_ = row >> 10, s = row & 1023;
  const int d0 = lane * 8;
  const int h = d0 >> 6;

  const unsigned short* yp = ybf + (size_t)row * kD + d0;
  const float* qp = q + (size_t)row * kD + d0;
  const int qm = qmask[((b_ * kH + h) % kB) * kS + s];

  u16x8 yv = *(const u16x8*)yp;
  float4 q0 = *(const float4*)qp, q1 = *(const float4*)(qp + 4);
  float vals[8];
#pragma unroll
  for (int jj = 0; jj < 8; ++jj) vals[jj] = bf2f(yv[jj]);
  float qs[8]   = { q0.x, q0.y, q0.z, q0.w, q1.x, q1.y, q1.z, q1.w };

  float sum = 0.f, ss = 0.f;
#pragma unroll
  for (int jj = 0; jj < 8; ++jj) {
    const float val = (qm ? vals[jj] : 0.f) + qs[jj];
    vals[jj] = val; sum += val; ss += val * val;
  }
#pragma unroll
  for (int off = 1; off < 64; off <<= 1) {
    sum += __shfl_xor(sum, off);
    ss  += __shfl_xor(ss, off);
  }
  const float mu = sum * (1.f / kD);
  const float var = ss * (1.f / kD) - mu * mu;
  const float rstd = rsqrtf(var + 1e-6f);

  float4 g0 = *(const float4*)(gamma + d0), g1 = *(const float4*)(gamma + d0 + 4);
  float4 be0 = *(const float4*)(beta + d0), be1 = *(const float4*)(beta + d0 + 4);
  float gs[8] = { g0.x, g0.y, g0.z, g0.w, g1.x, g1.y, g1.z, g1.w };
  float bs[8] = { be0.x, be0.y, be0.z, be0.w, be1.x, be1.y, be1.z, be1.w };

  float4 o0, o1;
  o0.x = gs[0] * (vals[0] - mu) * rstd + bs[0];
  o0.y = gs[1] * (vals[1] - mu) * rstd + bs[1];
  o0.z = gs[2] * (vals[2] - mu) * rstd + bs[2];
  o0.w = gs[3] * (vals[3] - mu) * rstd + bs[3];
  o1.x = gs[4] * (vals[4] - mu) * rstd + bs[4];
  o1.y = gs[5] * (vals[5] - mu) * rstd + bs[5];
  o1.z = gs[6] * (vals[6] - mu) * rstd + bs[6];
  o1.w = gs[7] * (vals[7] - mu) * rstd + bs[7];
  *(float4*)(out + (size_t)row * kD + d0) = o0;
  *(float4*)(out + (size_t)row * kD + d0 + 4) = o1;
}

extern "C" void kernel_launch(void* const* d_in, const int* in_sizes, int n_in,
                              void* d_out, int out_size, void* d_ws, size_t ws_size,
                              hipStream_t stream) {
  const float* q  = (const float*)d_in[0];
  const float* k  = (const float*)d_in[1];
  const float* v  = (const float*)d_in[2];
  const int* qmask = (const int*)d_in[3];
  const int* kmask = (const int*)d_in[4];
  const float* Wq = (const float*)d_in[5];
  const float* bq = (const float*)d_in[6];
  const float* Wk = (const float*)d_in[7];
  const float* bk = (const float*)d_in[8];
  const float* Wv = (const float*)d_in[9];
  const float* bv = (const float*)d_in[10];
  const float* gamma = (const float*)d_in[11];
  const float* beta  = (const float*)d_in[12];
  float* out = (float*)d_out;
  unsigned short* wsqkv = (unsigned short*)d_ws;        // 0..24MB: Q,K,V^T bf16
  unsigned short* ybf   = wsqkv + (size_t)3 * 4194304;  // 24..32.4MB: y bf16

  qkv_gemm_kernel<<<768, 256, 0, stream>>>(
      q, k, v, Wq, Wk, Wv, bq, bk, bv, wsqkv);
  attn_kernel<<<512, 256, 0, stream>>>(wsqkv, kmask, ybf);
  ln_kernel<<<2048, 256, 0, stream>>>(ybf, q, qmask, gamma, beta, out);
}

// Round 19
// 67.874 us; speedup vs baseline: 1.2126x; 1.0097x over previous
//
#include <hip/hip_runtime.h>
#include <hip/hip_bf16.h>
#include <stdint.h>

constexpr int kB = 8, kH = 8, kS = 1024, kD = 512, kDH = 64;
constexpr float kNeg = -1e9f;
constexpr float kScaleLog2e = 0.125f * 1.4426950408889634f;

typedef __attribute__((ext_vector_type(8))) short bf16x8;
typedef __attribute__((ext_vector_type(8))) unsigned short u16x8;
typedef __attribute__((ext_vector_type(4))) float f32x4;
typedef __attribute__((ext_vector_type(4))) unsigned short u16x4;

__device__ __forceinline__ unsigned short f2bf(float f) {
  union { float f; unsigned int u; } a; a.f = f;
  return (unsigned short)((a.u + 0x7FFFu + ((a.u >> 16) & 1u)) >> 16);
}
__device__ __forceinline__ float bf2f(unsigned short u) {
  union { unsigned int u; float f; } a; a.u = ((unsigned int)u) << 16;
  return a.f;
}
__device__ __forceinline__ unsigned int pk2bf(float lo, float hi) {
  union { __hip_bfloat162 h; unsigned int u; } cv;
  cv.h = __float22bfloat162_rn(make_float2(lo, hi));
  return cv.u;
}
// Pinned global loads (inline asm: cannot be sunk/CSE'd/re-materialized).
__device__ __forceinline__ uint4 gload16(const void* p) {
  uint4 r;
  asm volatile("global_load_dwordx4 %0, %1, off" : "=v"(r) : "v"(p));
  return r;
}
__device__ __forceinline__ int gload4(const void* p) {
  int r;
  asm volatile("global_load_dword %0, %1, off" : "=v"(r) : "v"(p));
  return r;
}
#define WAIT_VMCNT(N) do { \
  asm volatile("s_waitcnt vmcnt(" #N ")" ::: "memory"); \
  __builtin_amdgcn_sched_barrier(0); } while (0)

__device__ __forceinline__ uint4 cvt4(uint4 a, uint4 b) {
  uint4 r;
  r.x = pk2bf(__uint_as_float(a.x), __uint_as_float(a.y));
  r.y = pk2bf(__uint_as_float(a.z), __uint_as_float(a.w));
  r.z = pk2bf(__uint_as_float(b.x), __uint_as_float(b.y));
  r.w = pk2bf(__uint_as_float(b.z), __uint_as_float(b.w));
  return r;
}

#if __has_builtin(__builtin_amdgcn_exp2f)
#define EXP2F(x) __builtin_amdgcn_exp2f(x)
#else
#define EXP2F(x) exp2f(x)
#endif

// ---------------------------------------------------------------------------
// Kernel 1: C = relu(X @ W^T + bias). R18 verbatim: phase-split schedule
// (4 phases/K-step: ds_read frags; issue 4/16 next-tile loads; setprio(1);
// 8 MFMA; setprio(0); barrier), W f32->bf16 fused into B staging, 2-deep
// pinned prefetch with counted vmcnt(16).
//   Q,K: [b*H+h][s][64]; V: [b*H+h][d][s] with s k-permuted per 64-block.
// ---------------------------------------------------------------------------
__global__ __launch_bounds__(256)
void qkv_gemm_kernel(const float* __restrict__ xq, const float* __restrict__ xk,
                     const float* __restrict__ xv,
                     const float* __restrict__ wq, const float* __restrict__ wk,
                     const float* __restrict__ wv,
                     const float* __restrict__ bq, const float* __restrict__ bk,
                     const float* __restrict__ bv,
                     unsigned short* __restrict__ wsout)
{
  __shared__ __align__(16) unsigned short As[2][128][72];
  __shared__ __align__(16) unsigned short Bs[2][128][72];

  const int bid = blockIdx.x;
  const int xcd = bid & 7;
  const int j = bid >> 3;
  const int x = j & 3;
  const int g = (j >> 2) * 8 + xcd;        // 0..191
  const int z = g >> 6;                    // 0..2
  const int y = g & 63;                    // 0..63

  const float* X    = (z == 0) ? xq : (z == 1) ? xk : xv;
  const float* W    = (z == 0) ? wq : (z == 1) ? wk : wv;
  const float* bias = (z == 0) ? bq : (z == 1) ? bk : bv;
  unsigned short* out = wsout + (size_t)z * (kB * kS * kD);

  const int m0 = y * 128;
  const int n0 = x * 128;
  const int t = threadIdx.x;
  const int lane = t & 63;
  const int w = t >> 6;
  const int wr = w >> 1, wc = w & 1;
  const int l16 = lane & 15, lg = lane >> 4;

  const int row = t >> 3, c8 = (t & 7) * 8;
  const float* Xr = X + (size_t)(m0 + row) * kD + c8;
  const float* Wr = W + (size_t)(n0 + row) * kD + c8;

  f32x4 acc[4][4] = {};
  uint4 pa0, pa1, pa2, pa3, pa4, pa5, pa6, pa7;
  uint4 pb0l, pb0h, pb1l, pb1h, pb2l, pb2h, pb3l, pb3h;
  uint4 qa0, qa1, qa2, qa3, qa4, qa5, qa6, qa7;
  uint4 qb0l, qb0h, qb1l, qb1h, qb2l, qb2h, qb3l, qb3h;

  auto issueP = [&](int kt) {
    pa0 = gload16(Xr + kt);            pa1 = gload16(Xr + kt + 4);
    pa2 = gload16(Xr + 32 * kD + kt);  pa3 = gload16(Xr + 32 * kD + kt + 4);
    pa4 = gload16(Xr + 64 * kD + kt);  pa5 = gload16(Xr + 64 * kD + kt + 4);
    pa6 = gload16(Xr + 96 * kD + kt);  pa7 = gload16(Xr + 96 * kD + kt + 4);
    pb0l = gload16(Wr + kt);            pb0h = gload16(Wr + kt + 4);
    pb1l = gload16(Wr + 32 * kD + kt);  pb1h = gload16(Wr + 32 * kD + kt + 4);
    pb2l = gload16(Wr + 64 * kD + kt);  pb2h = gload16(Wr + 64 * kD + kt + 4);
    pb3l = gload16(Wr + 96 * kD + kt);  pb3h = gload16(Wr + 96 * kD + kt + 4);
  };
  auto issueQ = [&](int kt) {
    qa0 = gload16(Xr + kt);            qa1 = gload16(Xr + kt + 4);
    qa2 = gload16(Xr + 32 * kD + kt);  qa3 = gload16(Xr + 32 * kD + kt + 4);
    qa4 = gload16(Xr + 64 * kD + kt);  qa5 = gload16(Xr + 64 * kD + kt + 4);
    qa6 = gload16(Xr + 96 * kD + kt);  qa7 = gload16(Xr + 96 * kD + kt + 4);
    qb0l = gload16(Wr + kt);            qb0h = gload16(Wr + kt + 4);
    qb1l = gload16(Wr + 32 * kD + kt);  qb1h = gload16(Wr + 32 * kD + kt + 4);
    qb2l = gload16(Wr + 64 * kD + kt);  qb2h = gload16(Wr + 64 * kD + kt + 4);
    qb3l = gload16(Wr + 96 * kD + kt);  qb3h = gload16(Wr + 96 * kD + kt + 4);
  };
  auto issueP1 = [&](int kt) {
    pa0 = gload16(Xr + kt);            pa1 = gload16(Xr + kt + 4);
    pa2 = gload16(Xr + 32 * kD + kt);  pa3 = gload16(Xr + 32 * kD + kt + 4);
  };
  auto issueP2 = [&](int kt) {
    pa4 = gload16(Xr + 64 * kD + kt);  pa5 = gload16(Xr + 64 * kD + kt + 4);
    pa6 = gload16(Xr + 96 * kD + kt);  pa7 = gload16(Xr + 96 * kD + kt + 4);
  };
  auto issueP3 = [&](int kt) {
    pb0l = gload16(Wr + kt);            pb0h = gload16(Wr + kt + 4);
    pb1l = gload16(Wr + 32 * kD + kt);  pb1h = gload16(Wr + 32 * kD + kt + 4);
  };
  auto issueP4 = [&](int kt) {
    pb2l = gload16(Wr + 64 * kD + kt);  pb2h = gload16(Wr + 64 * kD + kt + 4);
    pb3l = gload16(Wr + 96 * kD + kt);  pb3h = gload16(Wr + 96 * kD + kt + 4);
  };
  auto issueQ1 = [&](int kt) {
    qa0 = gload16(Xr + kt);            qa1 = gload16(Xr + kt + 4);
    qa2 = gload16(Xr + 32 * kD + kt);  qa3 = gload16(Xr + 32 * kD + kt + 4);
  };
  auto issueQ2 = [&](int kt) {
    qa4 = gload16(Xr + 64 * kD + kt);  qa5 = gload16(Xr + 64 * kD + kt + 4);
    qa6 = gload16(Xr + 96 * kD + kt);  qa7 = gload16(Xr + 96 * kD + kt + 4);
  };
  auto issueQ3 = [&](int kt) {
    qb0l = gload16(Wr + kt);            qb0h = gload16(Wr + kt + 4);
    qb1l = gload16(Wr + 32 * kD + kt);  qb1h = gload16(Wr + 32 * kD + kt + 4);
  };
  auto issueQ4 = [&](int kt) {
    qb2l = gload16(Wr + 64 * kD + kt);  qb2h = gload16(Wr + 64 * kD + kt + 4);
    qb3l = gload16(Wr + 96 * kD + kt);  qb3h = gload16(Wr + 96 * kD + kt + 4);
  };
  auto writeP = [&]() {
    *(uint4*)&As[0][row][c8]      = cvt4(pa0, pa1);
    *(uint4*)&As[0][row + 32][c8] = cvt4(pa2, pa3);
    *(uint4*)&As[0][row + 64][c8] = cvt4(pa4, pa5);
    *(uint4*)&As[0][row + 96][c8] = cvt4(pa6, pa7);
    *(uint4*)&Bs[0][row][c8]      = cvt4(pb0l, pb0h);
    *(uint4*)&Bs[0][row + 32][c8] = cvt4(pb1l, pb1h);
    *(uint4*)&Bs[0][row + 64][c8] = cvt4(pb2l, pb2h);
    *(uint4*)&Bs[0][row + 96][c8] = cvt4(pb3l, pb3h);
  };
  auto writeQ = [&]() {
    *(uint4*)&As[1][row][c8]      = cvt4(qa0, qa1);
    *(uint4*)&As[1][row + 32][c8] = cvt4(qa2, qa3);
    *(uint4*)&As[1][row + 64][c8] = cvt4(qa4, qa5);
    *(uint4*)&As[1][row + 96][c8] = cvt4(qa6, qa7);
    *(uint4*)&Bs[1][row][c8]      = cvt4(qb0l, qb0h);
    *(uint4*)&Bs[1][row + 32][c8] = cvt4(qb1l, qb1h);
    *(uint4*)&Bs[1][row + 64][c8] = cvt4(qb2l, qb2h);
    *(uint4*)&Bs[1][row + 96][c8] = cvt4(qb3l, qb3h);
  };

#define COMPUTE_PHASED(BUF, KT, I1, I2, I3, I4)                               \
  do {                                                                        \
    bf16x8 av0, av1, av2, av3, bv0, bv1;                                      \
    av0 = *(const bf16x8*)&As[BUF][wr * 64 +  0 + l16][lg * 8];               \
    av1 = *(const bf16x8*)&As[BUF][wr * 64 + 16 + l16][lg * 8];               \
    av2 = *(const bf16x8*)&As[BUF][wr * 64 + 32 + l16][lg * 8];               \
    av3 = *(const bf16x8*)&As[BUF][wr * 64 + 48 + l16][lg * 8];               \
    bv0 = *(const bf16x8*)&Bs[BUF][wc * 64 +  0 + l16][lg * 8];               \
    bv1 = *(const bf16x8*)&Bs[BUF][wc * 64 + 16 + l16][lg * 8];               \
    if (KT >= 0) I1(KT);                                                      \
    __builtin_amdgcn_s_setprio(1);                                            \
    acc[0][0] = __builtin_amdgcn_mfma_f32_16x16x32_bf16(bv0, av0, acc[0][0], 0, 0, 0); \
    acc[1][0] = __builtin_amdgcn_mfma_f32_16x16x32_bf16(bv0, av1, acc[1][0], 0, 0, 0); \
    acc[2][0] = __builtin_amdgcn_mfma_f32_16x16x32_bf16(bv0, av2, acc[2][0], 0, 0, 0); \
    acc[3][0] = __builtin_amdgcn_mfma_f32_16x16x32_bf16(bv0, av3, acc[3][0], 0, 0, 0); \
    acc[0][1] = __builtin_amdgcn_mfma_f32_16x16x32_bf16(bv1, av0, acc[0][1], 0, 0, 0); \
    acc[1][1] = __builtin_amdgcn_mfma_f32_16x16x32_bf16(bv1, av1, acc[1][1], 0, 0, 0); \
    acc[2][1] = __builtin_amdgcn_mfma_f32_16x16x32_bf16(bv1, av2, acc[2][1], 0, 0, 0); \
    acc[3][1] = __builtin_amdgcn_mfma_f32_16x16x32_bf16(bv1, av3, acc[3][1], 0, 0, 0); \
    __builtin_amdgcn_s_setprio(0);                                            \
    __syncthreads();                                                          \
    bv0 = *(const bf16x8*)&Bs[BUF][wc * 64 + 32 + l16][lg * 8];               \
    bv1 = *(const bf16x8*)&Bs[BUF][wc * 64 + 48 + l16][lg * 8];               \
    if (KT >= 0) I2(KT);                                                      \
    __builtin_amdgcn_s_setprio(1);                                            \
    acc[0][2] = __builtin_amdgcn_mfma_f32_16x16x32_bf16(bv0, av0, acc[0][2], 0, 0, 0); \
    acc[1][2] = __builtin_amdgcn_mfma_f32_16x16x32_bf16(bv0, av1, acc[1][2], 0, 0, 0); \
    acc[2][2] = __builtin_amdgcn_mfma_f32_16x16x32_bf16(bv0, av2, acc[2][2], 0, 0, 0); \
    acc[3][2] = __builtin_amdgcn_mfma_f32_16x16x32_bf16(bv0, av3, acc[3][2], 0, 0, 0); \
    acc[0][3] = __builtin_amdgcn_mfma_f32_16x16x32_bf16(bv1, av0, acc[0][3], 0, 0, 0); \
    acc[1][3] = __builtin_amdgcn_mfma_f32_16x16x32_bf16(bv1, av1, acc[1][3], 0, 0, 0); \
    acc[2][3] = __builtin_amdgcn_mfma_f32_16x16x32_bf16(bv1, av2, acc[2][3], 0, 0, 0); \
    acc[3][3] = __builtin_amdgcn_mfma_f32_16x16x32_bf16(bv1, av3, acc[3][3], 0, 0, 0); \
    __builtin_amdgcn_s_setprio(0);                                            \
    __syncthreads();                                                          \
    av0 = *(const bf16x8*)&As[BUF][wr * 64 +  0 + l16][32 + lg * 8];          \
    av1 = *(const bf16x8*)&As[BUF][wr * 64 + 16 + l16][32 + lg * 8];          \
    av2 = *(const bf16x8*)&As[BUF][wr * 64 + 32 + l16][32 + lg * 8];          \
    av3 = *(const bf16x8*)&As[BUF][wr * 64 + 48 + l16][32 + lg * 8];          \
    bv0 = *(const bf16x8*)&Bs[BUF][wc * 64 +  0 + l16][32 + lg * 8];          \
    bv1 = *(const bf16x8*)&Bs[BUF][wc * 64 + 16 + l16][32 + lg * 8];          \
    if (KT >= 0) I3(KT);                                                      \
    __builtin_amdgcn_s_setprio(1);                                            \
    acc[0][0] = __builtin_amdgcn_mfma_f32_16x16x32_bf16(bv0, av0, acc[0][0], 0, 0, 0); \
    acc[1][0] = __builtin_amdgcn_mfma_f32_16x16x32_bf16(bv0, av1, acc[1][0], 0, 0, 0); \
    acc[2][0] = __builtin_amdgcn_mfma_f32_16x16x32_bf16(bv0, av2, acc[2][0], 0, 0, 0); \
    acc[3][0] = __builtin_amdgcn_mfma_f32_16x16x32_bf16(bv0, av3, acc[3][0], 0, 0, 0); \
    acc[0][1] = __builtin_amdgcn_mfma_f32_16x16x32_bf16(bv1, av0, acc[0][1], 0, 0, 0); \
    acc[1][1] = __builtin_amdgcn_mfma_f32_16x16x32_bf16(bv1, av1, acc[1][1], 0, 0, 0); \
    acc[2][1] = __builtin_amdgcn_mfma_f32_16x16x32_bf16(bv1, av2, acc[2][1], 0, 0, 0); \
    acc[3][1] = __builtin_amdgcn_mfma_f32_16x16x32_bf16(bv1, av3, acc[3][1], 0, 0, 0); \
    __builtin_amdgcn_s_setprio(0);                                            \
    __syncthreads();                                                          \
    bv0 = *(const bf16x8*)&Bs[BUF][wc * 64 + 32 + l16][32 + lg * 8];          \
    bv1 = *(const bf16x8*)&Bs[BUF][wc * 64 + 48 + l16][32 + lg * 8];          \
    if (KT >= 0) I4(KT);                                                      \
    __builtin_amdgcn_s_setprio(1);                                            \
    acc[0][2] = __builtin_amdgcn_mfma_f32_16x16x32_bf16(bv0, av0, acc[0][2], 0, 0, 0); \
    acc[1][2] = __builtin_amdgcn_mfma_f32_16x16x32_bf16(bv0, av1, acc[1][2], 0, 0, 0); \
    acc[2][2] = __builtin_amdgcn_mfma_f32_16x16x32_bf16(bv0, av2, acc[2][2], 0, 0, 0); \
    acc[3][2] = __builtin_amdgcn_mfma_f32_16x16x32_bf16(bv0, av3, acc[3][2], 0, 0, 0); \
    acc[0][3] = __builtin_amdgcn_mfma_f32_16x16x32_bf16(bv1, av0, acc[0][3], 0, 0, 0); \
    acc[1][3] = __builtin_amdgcn_mfma_f32_16x16x32_bf16(bv1, av1, acc[1][3], 0, 0, 0); \
    acc[2][3] = __builtin_amdgcn_mfma_f32_16x16x32_bf16(bv1, av2, acc[2][3], 0, 0, 0); \
    acc[3][3] = __builtin_amdgcn_mfma_f32_16x16x32_bf16(bv1, av3, acc[3][3], 0, 0, 0); \
    __builtin_amdgcn_s_setprio(0);                                            \
  } while (0)

  issueP(0);
  issueQ(64);
#pragma unroll
  for (int i = 0; i < 6; i += 2) {
    WAIT_VMCNT(16);
    writeP();
    __syncthreads();
    COMPUTE_PHASED(0, (i + 2) * 64, issueP1, issueP2, issueP3, issueP4);
    WAIT_VMCNT(16);
    writeQ();
    __syncthreads();
    COMPUTE_PHASED(1, (i + 3) * 64, issueQ1, issueQ2, issueQ3, issueQ4);
  }
  WAIT_VMCNT(16);
  writeP();
  __syncthreads();
  COMPUTE_PHASED(0, -1, issueP1, issueP2, issueP3, issueP4);
  WAIT_VMCNT(0);
  writeQ();
  __syncthreads();
  COMPUTE_PHASED(1, -1, issueQ1, issueQ2, issueQ3, issueQ4);
#undef COMPUTE_PHASED

  if (z == 2) {
    const int mmbase = m0 + wr * 64;
    const int b_ = mmbase >> 10, sbase = mmbase & 1023;
#pragma unroll
    for (int nf = 0; nf < 4; ++nf) {
#pragma unroll
      for (int r = 0; r < 4; ++r) {
        const int n = n0 + wc * 64 + nf * 16 + lg * 4 + r;
        const float bval = bias[n];
        const int h = n >> 6, dd = n & 63;
        u16x4 pk;
#pragma unroll
        for (int mf = 0; mf < 4; ++mf) {
          float vv = acc[mf][nf][r] + bval;
          vv = vv > 0.f ? vv : 0.f;
          pk[mf] = f2bf(vv);
        }
        *(u16x4*)&out[((size_t)((b_ * kH + h) * kDH + dd)) * kS + sbase + l16 * 4] = pk;
      }
    }
  } else {
#pragma unroll
    for (int mf = 0; mf < 4; ++mf) {
      const int mm = m0 + wr * 64 + mf * 16 + l16;
      const int b_ = mm >> 10, s = mm & 1023;
#pragma unroll
      for (int nf = 0; nf < 4; ++nf) {
        const int nbase = n0 + wc * 64 + nf * 16 + lg * 4;
        const int h = nbase >> 6, dd = nbase & 63;
        u16x4 pk;
#pragma unroll
        for (int r = 0; r < 4; ++r) {
          float vv = acc[mf][nf][r] + bias[nbase + r];
          vv = vv > 0.f ? vv : 0.f;
          pk[r] = f2bf(vv);
        }
        *(u16x4*)&out[((size_t)(b_ * kH + h) * kS + s) * kDH + dd] = pk;
      }
    }
  }
}

// ---------------------------------------------------------------------------
// Kernel 2: flash attention (R18 structure) with LDS row pad 72 -> 68:
// 55.8 KB -> 51.5 KB per block => 3 blocks/CU instead of 2 (+50% waves for
// latency hiding; R18 counters: Occupancy 21%, both pipes <25% => latency-
// bound). Stride 136 B keeps the 16-rows/col ds_read_b128 pattern at the
// free 2-way bank-alias level ((row*34+c)%32 spans 16 banks).
// ---------------------------------------------------------------------------
__global__ __launch_bounds__(256)
void attn_kernel(const unsigned short* __restrict__ ws,
                 const int* __restrict__ key_mask,
                 unsigned short* __restrict__ ybf)
{
  __shared__ __align__(16) unsigned short Ks[2][64][68];
  __shared__ __align__(16) unsigned short Vts[2][64][68];
  __shared__ __align__(16) unsigned short Ps[4][32][68];
  __shared__ float kmadd[2][64];

  const unsigned short* Qw = ws;
  const unsigned short* Kw = ws + (size_t)1 * kB * kS * kD;
  const unsigned short* Vw = ws + (size_t)2 * kB * kS * kD;

  const int bid = blockIdx.x;
  const int xcd = bid & 7;
  const int j = bid >> 3;
  const int qx = j & 7;
  const int bh = (j >> 3) * 8 + xcd;

  const int q0 = qx * 128;
  const int t = threadIdx.x;
  const int w = t >> 6, lane = t & 63;
  const int l16 = lane & 15, lg = lane >> 4;
  const int b_ = bh / kH, h = bh % kH;

  const unsigned short* Qb = Qw + ((size_t)bh * kS + q0) * kDH;
  const unsigned short* Kb = Kw + (size_t)bh * kS * kDH;
  const unsigned short* Vb = Vw + (size_t)bh * kDH * kS;
  const int* km = key_mask + (bh % kB) * kS;

  const int srow = t >> 3, sc8 = (t & 7) * 8;
  const unsigned short* KbR0 = Kb + (size_t)srow * kDH + sc8;
  const unsigned short* KbR1 = Kb + (size_t)(srow + 32) * kDH + sc8;
  const unsigned short* VbR0 = Vb + (size_t)srow * kS + sc8;
  const unsigned short* VbR1 = Vb + (size_t)(srow + 32) * kS + sc8;

  bf16x8 aq[2][2];
#pragma unroll
  for (int u = 0; u < 2; ++u)
#pragma unroll
    for (int kk = 0; kk < 2; ++kk)
      aq[u][kk] = *(const bf16x8*)(Qb + (size_t)(w * 32 + u * 16 + l16) * kDH + kk * 32 + lg * 8);

  bf16x8 vone;
#pragma unroll
  for (int jj = 0; jj < 8; ++jj) vone[jj] = (short)0x3F80;

  f32x4 o[2][4] = {};
  f32x4 lacc[2] = {};

  uint4 ka0, ka1, va0, va1; int kma;
  uint4 kb0, kb1, vb0, vb1; int kmb;

  auto issueA = [&](int kv0) {
    ka0 = gload16(KbR0 + (size_t)kv0 * kDH);
    ka1 = gload16(KbR1 + (size_t)kv0 * kDH);
    va0 = gload16(VbR0 + kv0);
    va1 = gload16(VbR1 + kv0);
    kma = gload4(km + kv0 + (t & 63));
  };
  auto issueB = [&](int kv0) {
    kb0 = gload16(KbR0 + (size_t)kv0 * kDH);
    kb1 = gload16(KbR1 + (size_t)kv0 * kDH);
    vb0 = gload16(VbR0 + kv0);
    vb1 = gload16(VbR1 + kv0);
    kmb = gload4(km + kv0 + (t & 63));
  };
  auto writeA = [&]() {
    *(uint4*)&Ks[0][srow][sc8]       = ka0;
    *(uint4*)&Ks[0][srow + 32][sc8]  = ka1;
    *(uint4*)&Vts[0][srow][sc8]      = va0;
    *(uint4*)&Vts[0][srow + 32][sc8] = va1;
    if (t < 64) kmadd[0][t] = kma ? 0.f : kNeg;
  };
  auto writeB = [&]() {
    *(uint4*)&Ks[1][srow][sc8]       = kb0;
    *(uint4*)&Ks[1][srow + 32][sc8]  = kb1;
    *(uint4*)&Vts[1][srow][sc8]      = vb0;
    *(uint4*)&Vts[1][srow + 32][sc8] = vb1;
    if (t < 64) kmadd[1][t] = kmb ? 0.f : kNeg;
  };
  auto compute = [&](int buf) {
    f32x4 sc[2][4] = {};
    __builtin_amdgcn_s_setprio(1);
#pragma unroll
    for (int kk = 0; kk < 2; ++kk) {
#pragma unroll
      for (int nf = 0; nf < 4; ++nf) {
        bf16x8 bfr = *(const bf16x8*)&Ks[buf][nf * 16 + l16][kk * 32 + lg * 8];
#pragma unroll
        for (int u = 0; u < 2; ++u)
          sc[u][nf] = __builtin_amdgcn_mfma_f32_16x16x32_bf16(aq[u][kk], bfr, sc[u][nf], 0, 0, 0);
      }
    }
    __builtin_amdgcn_s_setprio(0);
    float madd[4];
#pragma unroll
    for (int nf = 0; nf < 4; ++nf) madd[nf] = kmadd[buf][nf * 16 + l16];
#pragma unroll
    for (int u = 0; u < 2; ++u) {
#pragma unroll
      for (int r = 0; r < 4; ++r) {
        const float p0 = EXP2F(fmaf(sc[u][0][r], kScaleLog2e, madd[0]));
        const float p1 = EXP2F(fmaf(sc[u][1][r], kScaleLog2e, madd[1]));
        const float p2 = EXP2F(fmaf(sc[u][2][r], kScaleLog2e, madd[2]));
        const float p3 = EXP2F(fmaf(sc[u][3][r], kScaleLog2e, madd[3]));
        const int prow = u * 16 + lg * 4 + r;
        uint2 pw;
        pw.x = __builtin_amdgcn_perm(__float_as_uint(p1), __float_as_uint(p0), 0x07060302u);
        pw.y = __builtin_amdgcn_perm(__float_as_uint(p3), __float_as_uint(p2), 0x07060302u);
        *(uint2*)&Ps[w][prow][l16 * 4] = pw;
      }
    }
    __builtin_amdgcn_s_setprio(1);
#pragma unroll
    for (int kk = 0; kk < 2; ++kk) {
      bf16x8 a0 = *(const bf16x8*)&Ps[w][l16][kk * 32 + lg * 8];
      bf16x8 a1 = *(const bf16x8*)&Ps[w][16 + l16][kk * 32 + lg * 8];
#pragma unroll
      for (int nd = 0; nd < 4; ++nd) {
        bf16x8 bfr = *(const bf16x8*)&Vts[buf][nd * 16 + l16][kk * 32 + lg * 8];
        o[0][nd] = __builtin_amdgcn_mfma_f32_16x16x32_bf16(a0, bfr, o[0][nd], 0, 0, 0);
        o[1][nd] = __builtin_amdgcn_mfma_f32_16x16x32_bf16(a1, bfr, o[1][nd], 0, 0, 0);
      }
      lacc[0] = __builtin_amdgcn_mfma_f32_16x16x32_bf16(a0, vone, lacc[0], 0, 0, 0);
      lacc[1] = __builtin_amdgcn_mfma_f32_16x16x32_bf16(a1, vone, lacc[1], 0, 0, 0);
    }
    __builtin_amdgcn_s_setprio(0);
  };

  issueA(0);
  issueB(64);
  for (int i = 0; i < 14; i += 2) {
    WAIT_VMCNT(5);
    writeA();
    issueA((i + 2) * 64);
    __syncthreads();
    compute(0);
    WAIT_VMCNT(5);
    writeB();
    issueB((i + 3) * 64);
    __syncthreads();
    compute(1);
  }
  WAIT_VMCNT(5);
  writeA();
  __syncthreads();
  compute(0);
  WAIT_VMCNT(0);
  writeB();
  __syncthreads();
  compute(1);

#pragma unroll
  for (int u = 0; u < 2; ++u) {
    float rinv[4];
#pragma unroll
    for (int r = 0; r < 4; ++r) rinv[r] = 1.f / lacc[u][r];
#pragma unroll
    for (int nd = 0; nd < 4; ++nd) {
#pragma unroll
      for (int r = 0; r < 4; ++r) {
        const int srowq = q0 + w * 32 + u * 16 + lg * 4 + r;
        ybf[((size_t)b_ * kS + srowq) * kD + h * kDH + nd * 16 + l16] =
            f2bf(o[u][nd][r] * rinv[r]);
      }
    }
  }
}

// ---------------------------------------------------------------------------
// Kernel 3: out = LN(qmask*y + q) * gamma + beta. y read as bf16 from ws.
// ---------------------------------------------------------------------------
__global__ __launch_bounds__(256)
void ln_kernel(const unsigned short* __restrict__ ybf, const float* __restrict__ q,
               const int* __restrict__ qmask,
               const float* __restrict__ gamma, const float* __restrict__ beta,
               float* __restrict__ out)
{
  const int w = threadIdx.x >> 6, lane = threadIdx.x & 63;
  const int row = blockIdx.x * 4 + w;            // 0..8191
  const int b_ = row >> 10, s = row & 1023;
  const int d0 = lane * 8;
  const int h = d0 >> 6;

  const unsigned short* yp = ybf + (size_t)row * kD + d0;
  const float* qp = q + (size_t)row * kD + d0;
  const int qm = qmask[((b_ * kH + h) % kB) * kS + s];

  u16x8 yv = *(const u16x8*)yp;
  float4 q0 = *(const float4*)qp, q1 = *(const float4*)(qp + 4);
  float vals[8];
#pragma unroll
  for (int jj = 0; jj < 8; ++jj) vals[jj] = bf2f(yv[jj]);
  float qs[8]   = { q0.x, q0.y, q0.z, q0.w, q1.x, q1.y, q1.z, q1.w };

  float sum = 0.f, ss = 0.f;
#pragma unroll
  for (int jj = 0; jj < 8; ++jj) {
    const float val = (qm ? vals[jj] : 0.f) + qs[jj];
    vals[jj] = val; sum += val; ss += val * val;
  }
#pragma unroll
  for (int off = 1; off < 64; off <<= 1) {
    sum += __shfl_xor(sum, off);
    ss  += __shfl_xor(ss, off);
  }
  const float mu = sum * (1.f / kD);
  const float var = ss * (1.f / kD) - mu * mu;
  const float rstd = rsqrtf(var + 1e-6f);

  float4 g0 = *(const float4*)(gamma + d0), g1 = *(const float4*)(gamma + d0 + 4);
  float4 be0 = *(const float4*)(beta + d0), be1 = *(const float4*)(beta + d0 + 4);
  float gs[8] = { g0.x, g0.y, g0.z, g0.w, g1.x, g1.y, g1.z, g1.w };
  float bs[8] = { be0.x, be0.y, be0.z, be0.w, be1.x, be1.y, be1.z, be1.w };

  float4 o0, o1;
  o0.x = gs[0] * (vals[0] - mu) * rstd + bs[0];
  o0.y = gs[1] * (vals[1] - mu) * rstd + bs[1];
  o0.z = gs[2] * (vals[2] - mu) * rstd + bs[2];
  o0.w = gs[3] * (vals[3] - mu) * rstd + bs[3];
  o1.x = gs[4] * (vals[4] - mu) * rstd + bs[4];
  o1.y = gs[5] * (vals[5] - mu) * rstd + bs[5];
  o1.z = gs[6] * (vals[6] - mu) * rstd + bs[6];
  o1.w = gs[7] * (vals[7] - mu) * rstd + bs[7];
  *(float4*)(out + (size_t)row * kD + d0) = o0;
  *(float4*)(out + (size_t)row * kD + d0 + 4) = o1;
}

extern "C" void kernel_launch(void* const* d_in, const int* in_sizes, int n_in,
                              void* d_out, int out_size, void* d_ws, size_t ws_size,
                              hipStream_t stream) {
  const float* q  = (const float*)d_in[0];
  const float* k  = (const float*)d_in[1];
  const float* v  = (const float*)d_in[2];
  const int* qmask = (const int*)d_in[3];
  const int* kmask = (const int*)d_in[4];
  const float* Wq = (const float*)d_in[5];
  const float* bq = (const float*)d_in[6];
  const float* Wk = (const float*)d_in[7];
  const float* bk = (const float*)d_in[8];
  const float* Wv = (const float*)d_in[9];
  const float* bv = (const float*)d_in[10];
  const float* gamma = (const float*)d_in[11];
  const float* beta  = (const float*)d_in[12];
  float* out = (float*)d_out;
  unsigned short* wsqkv = (unsigned short*)d_ws;        // 0..24MB: Q,K,V^T bf16
  unsigned short* ybf   = wsqkv + (size_t)3 * 4194304;  // 24..32.4MB: y bf16

  qkv_gemm_kernel<<<768, 256, 0, stream>>>(
      q, k, v, Wq, Wk, Wv, bq, bk, bv, wsqkv);
  attn_kernel<<<512, 256, 0, stream>>>(wsqkv, kmask, ybf);
  ln_kernel<<<2048, 256, 0, stream>>>(ybf, q, qmask, gamma, beta, out);
}